// Round 4
// baseline (1537.114 us; speedup 1.0000x reference)
//
#include <hip/hip_runtime.h>

#define IN_DIM 128
#define HID 64
#define MAXBKT 1600          // >= ceil(N/64); N=100000 -> 1563

// ---------------- per-node degree histogram ----------------
__global__ __launch_bounds__(256) void k_hist(const int* __restrict__ dst,
                                              int* __restrict__ cnt, int E) {
    int e = blockIdx.x * 256 + threadIdx.x;
    if (e < E) atomicAdd(&cnt[dst[e]], 1);
}

// ---------------- dis = rsqrt(1 + deg) ----------------
__global__ __launch_bounds__(256) void k_dis(const int* __restrict__ cnt,
                                             float* __restrict__ dis, int N) {
    int i = blockIdx.x * 256 + threadIdx.x;
    if (i < N) dis[i] = rsqrtf((float)cnt[i] + 1.0f);
}

// ---------------- bucket totals: wave per bucket reduces 64 node counts ----------------
__global__ __launch_bounds__(256) void k_bktcnt(const int* __restrict__ cnt,
                                                int* __restrict__ bktTotal,
                                                int N, int NBKT) {
    int lane = threadIdx.x & 63;
    int b = (blockIdx.x * 256 + threadIdx.x) >> 6;
    if (b >= NBKT) return;
    int node = b * 64 + lane;
    int v = (node < N) ? cnt[node] : 0;
#pragma unroll
    for (int off = 32; off >= 1; off >>= 1) v += __shfl_down(v, off, 64);
    if (lane == 0) bktTotal[b] = v;
}

// ---------------- single-block exclusive scan over buckets ----------------
__global__ __launch_bounds__(512) void k_bktscan(const int* __restrict__ bktTotal,
                                                 int* __restrict__ bktStart,
                                                 int* __restrict__ cursorB, int NBKT) {
    __shared__ int part[512];
    int t = threadIdx.x;
    int v[4]; int sum = 0;
#pragma unroll
    for (int q = 0; q < 4; ++q) {
        int i = t * 4 + q;
        v[q] = (i < NBKT) ? bktTotal[i] : 0;
        sum += v[q];
    }
    part[t] = sum;
    __syncthreads();
    for (int off = 1; off < 512; off <<= 1) {
        int a = (t >= off) ? part[t - off] : 0;
        __syncthreads();
        part[t] += a;
        __syncthreads();
    }
    int running = part[t] - sum;   // exclusive prefix of this thread's chunk
#pragma unroll
    for (int q = 0; q < 4; ++q) {
        int i = t * 4 + q;
        if (i < NBKT) { bktStart[i] = running; cursorB[i] = running; }
        running += v[q];
    }
    if (t == 511) bktStart[NBKT] = running;   // == E
}

// ---------------- block-level counting sort into bucket-ordered edge array ----------------
// tmp[pos] = { src | (dloc<<17), norm }  where dloc = dst & 63
#define EPB 8192
__global__ __launch_bounds__(256) void k_part(const int* __restrict__ src,
                                              const int* __restrict__ dst,
                                              const float* __restrict__ dis,
                                              int* __restrict__ cursorB,
                                              int2* __restrict__ tmp,
                                              int E, int NBKT) {
    __shared__ int bcnt[MAXBKT];
    __shared__ int bbase[MAXBKT];
    int tid = threadIdx.x;
    int e0 = blockIdx.x * EPB;
    int e1 = min(e0 + EPB, E);
    for (int i = tid; i < NBKT; i += 256) bcnt[i] = 0;
    __syncthreads();
    // phase A: local histogram
    for (int e = e0 + tid; e < e1; e += 256) atomicAdd(&bcnt[dst[e] >> 6], 1);
    __syncthreads();
    // phase B: reserve contiguous runs
    for (int i = tid; i < NBKT; i += 256) {
        int c = bcnt[i];
        bbase[i] = c ? atomicAdd(&cursorB[i], c) : 0;
    }
    __syncthreads();
    for (int i = tid; i < NBKT; i += 256) bcnt[i] = 0;
    __syncthreads();
    // phase C: place edges (reads L2-hot), packed payload
    for (int e = e0 + tid; e < e1; e += 256) {
        int s = src[e], d = dst[e];
        int b = d >> 6;
        int slot = bbase[b] + atomicAdd(&bcnt[b], 1);
        int2 pk;
        pk.x = s | ((d & 63) << 17);
        pk.y = __float_as_int(dis[s] * dis[d]);
        tmp[slot] = pk;
    }
}

// ---------------- register-tiled transform: H[N,64] = X[N,K] @ W[K,64] ----------------
template <int K>
__global__ __launch_bounds__(256) void k_mmrt(const float* __restrict__ X,
                                              const float* __restrict__ W,
                                              float* __restrict__ H, int N) {
    constexpr int BR = 128, BK = 32, S = 132;
    __shared__ float Xs[BK * S];
    __shared__ float Ws[BK * 64];
    const int tid = threadIdx.x;
    const int c0 = (tid & 15) * 4;
    const int row0 = (tid >> 4) * 8;
    const int blockRow = blockIdx.x * BR;
    float acc[8][4];
#pragma unroll
    for (int r = 0; r < 8; ++r)
#pragma unroll
        for (int c = 0; c < 4; ++c) acc[r][c] = 0.f;

    for (int k0 = 0; k0 < K; k0 += BK) {
        int i = tid;
#pragma unroll
        for (int it = 0; it < 4; ++it, i += 256) {
            int row = i >> 3, kq = i & 7;
            int gr = blockRow + row;
            if (gr >= N) gr = N - 1;
            float4 v = *(const float4*)&X[(size_t)gr * K + k0 + kq * 4];
            Xs[(kq * 4 + 0) * S + row] = v.x;
            Xs[(kq * 4 + 1) * S + row] = v.y;
            Xs[(kq * 4 + 2) * S + row] = v.z;
            Xs[(kq * 4 + 3) * S + row] = v.w;
        }
        int j2 = tid;
#pragma unroll
        for (int it = 0; it < 2; ++it, j2 += 256) {
            int k = j2 >> 4, cq = j2 & 15;
            *(float4*)&Ws[k * 64 + cq * 4] =
                *(const float4*)&W[(size_t)(k0 + k) * 64 + cq * 4];
        }
        __syncthreads();
#pragma unroll
        for (int kk = 0; kk < BK; kk += 4) {
            float4 b[4], alo[4], ahi[4];
#pragma unroll
            for (int j = 0; j < 4; ++j) {
                b[j]   = *(const float4*)&Ws[(kk + j) * 64 + c0];
                alo[j] = *(const float4*)&Xs[(kk + j) * S + row0];
                ahi[j] = *(const float4*)&Xs[(kk + j) * S + row0 + 4];
            }
#pragma unroll
            for (int j = 0; j < 4; ++j) {
                const float a_[8] = {alo[j].x, alo[j].y, alo[j].z, alo[j].w,
                                     ahi[j].x, ahi[j].y, ahi[j].z, ahi[j].w};
#pragma unroll
                for (int r = 0; r < 8; ++r) {
                    acc[r][0] += a_[r] * b[j].x;
                    acc[r][1] += a_[r] * b[j].y;
                    acc[r][2] += a_[r] * b[j].z;
                    acc[r][3] += a_[r] * b[j].w;
                }
            }
        }
        __syncthreads();
    }
#pragma unroll
    for (int r = 0; r < 8; ++r) {
        int gr = blockRow + row0 + r;
        if (gr < N) *(float4*)&H[(size_t)gr * 64 + c0] = *(float4*)&acc[r][0];
    }
}

// ---------------- aggregation: block per bucket, 64x64 LDS accumulator ----------------
// out[i,:] = relu( b + H[i,:]*dis[i]^2 + sum_edges H[src,:]*norm )
__global__ __launch_bounds__(256) void k_agg(const float* __restrict__ H,
                                             const int2* __restrict__ tmp,
                                             const int* __restrict__ bktStart,
                                             const float* __restrict__ dis,
                                             const float* __restrict__ bias,
                                             float* __restrict__ out, int N) {
    __shared__ float accum[64 * 64];
    int tid = threadIdx.x;
    int b = blockIdx.x;
    int node0 = b << 6;
    for (int i = tid; i < 4096; i += 256) accum[i] = 0.f;
    __syncthreads();

    int r0 = bktStart[b], r1 = bktStart[b + 1];
    int lane = tid & 63;
    int wv = tid >> 6;
    for (int base = r0 + wv * 64; base < r1; base += 256) {
        int cnt = min(64, r1 - base);
        int2 pk = (lane < cnt) ? tmp[base + lane] : make_int2(0, 0);
        int xs = pk.x, ys = pk.y;
        int j = 0;
        for (; j + 4 <= cnt; j += 4) {
            int x0 = __shfl(xs, j, 64),     x1 = __shfl(xs, j + 1, 64);
            int x2 = __shfl(xs, j + 2, 64), x3 = __shfl(xs, j + 3, 64);
            int y0 = __shfl(ys, j, 64),     y1 = __shfl(ys, j + 1, 64);
            int y2 = __shfl(ys, j + 2, 64), y3 = __shfl(ys, j + 3, 64);
            float h0 = H[(size_t)(x0 & 0x1FFFF) * 64 + lane];
            float h1 = H[(size_t)(x1 & 0x1FFFF) * 64 + lane];
            float h2 = H[(size_t)(x2 & 0x1FFFF) * 64 + lane];
            float h3 = H[(size_t)(x3 & 0x1FFFF) * 64 + lane];
            atomicAdd(&accum[((x0 >> 17) << 6) + lane], h0 * __int_as_float(y0));
            atomicAdd(&accum[((x1 >> 17) << 6) + lane], h1 * __int_as_float(y1));
            atomicAdd(&accum[((x2 >> 17) << 6) + lane], h2 * __int_as_float(y2));
            atomicAdd(&accum[((x3 >> 17) << 6) + lane], h3 * __int_as_float(y3));
        }
        for (; j < cnt; ++j) {
            int xj = __shfl(xs, j, 64);
            int yj = __shfl(ys, j, 64);
            float hj = H[(size_t)(xj & 0x1FFFF) * 64 + lane];
            atomicAdd(&accum[((xj >> 17) << 6) + lane], hj * __int_as_float(yj));
        }
    }
    __syncthreads();
    for (int idx = tid; idx < 4096; idx += 256) {
        int node = node0 + (idx >> 6);
        if (node >= N) break;
        int f = idx & 63;
        float d = dis[node];
        float val = accum[idx] + H[(size_t)node * 64 + f] * d * d + bias[f];
        out[(size_t)node * 64 + f] = fmaxf(val, 0.f);
    }
}

// ---------------- layer 3: col[i] = H[i,:] . W3 ----------------
__global__ __launch_bounds__(256) void k_mm1col(const float* __restrict__ H,
                                                const float* __restrict__ W3,
                                                float* __restrict__ col, int N) {
    int lane = threadIdx.x & 63;
    int node = (blockIdx.x * 256 + threadIdx.x) >> 6;
    if (node >= N) return;
    float v = H[(size_t)node * 64 + lane] * W3[lane];
#pragma unroll
    for (int off = 32; off >= 1; off >>= 1) v += __shfl_down(v, off, 64);
    if (lane == 0) col[node] = v;
}

// ---------------- layer-3 aggregation: block per bucket, 64-float LDS accum ----------------
__global__ __launch_bounds__(256) void k_agg1(const float* __restrict__ col,
                                              const int2* __restrict__ tmp,
                                              const int* __restrict__ bktStart,
                                              const float* __restrict__ dis,
                                              const float* __restrict__ b3,
                                              float* __restrict__ out, int N) {
    __shared__ float acc1[64];
    int tid = threadIdx.x;
    int b = blockIdx.x;
    int node0 = b << 6;
    if (tid < 64) acc1[tid] = 0.f;
    __syncthreads();
    int r0 = bktStart[b], r1 = bktStart[b + 1];
    for (int e = r0 + tid; e < r1; e += 256) {
        int2 pk = tmp[e];
        int s = pk.x & 0x1FFFF;
        int dl = pk.x >> 17;
        atomicAdd(&acc1[dl], col[s] * __int_as_float(pk.y));
    }
    __syncthreads();
    if (tid < 64) {
        int node = node0 + tid;
        if (node < N) {
            float d = dis[node];
            out[node] = acc1[tid] + col[node] * d * d + b3[0];
        }
    }
}

extern "C" void kernel_launch(void* const* d_in, const int* in_sizes, int n_in,
                              void* d_out, int out_size, void* d_ws, size_t ws_size,
                              hipStream_t stream) {
    const float* x  = (const float*)d_in[0];
    const int*   ei = (const int*)d_in[1];
    const float* W1 = (const float*)d_in[2];
    const float* b1 = (const float*)d_in[3];
    const float* W2 = (const float*)d_in[4];
    const float* b2 = (const float*)d_in[5];
    const float* W3 = (const float*)d_in[6];
    const float* b3 = (const float*)d_in[7];
    float* out = (float*)d_out;

    const int N = in_sizes[0] / IN_DIM;     // 100000
    const int E = in_sizes[1] / 2;          // 1600000
    const int* src = ei;
    const int* dst = ei + E;
    const int NBKT = (N + 63) / 64;         // 1563

    // ---- workspace layout ----
    char* w = (char*)d_ws;
    auto alloc = [&](size_t bytes) {
        char* p = w;
        w += (bytes + 1023) & ~(size_t)1023;
        return p;
    };
    float* dis      = (float*)alloc((size_t)N * 4);
    float* bufA     = (float*)alloc((size_t)N * 64 * 4);
    float* bufB     = (float*)alloc((size_t)N * 64 * 4);
    float* col      = (float*)alloc((size_t)N * 4);
    int*   cnt      = (int*)alloc((size_t)N * 4);
    int*   bktTotal = (int*)alloc((size_t)MAXBKT * 4);
    int*   bktStart = (int*)alloc((size_t)(MAXBKT + 1) * 4);
    int*   cursorB  = (int*)alloc((size_t)MAXBKT * 4);
    int2*  tmp      = (int2*)alloc((size_t)E * 8);

    const int NB_N  = (N + 255) / 256;
    const int NB_E  = (E + 255) / 256;
    const int NB_MM = (N + 127) / 128;
    const int NB_WV = (N * 64 + 255) / 256;
    const int NB_BK = (NBKT * 64 + 255) / 256;
    const int NB_PT = (E + EPB - 1) / EPB;

    // ---- degree + bucket partition ----
    hipMemsetAsync(cnt, 0, (size_t)N * sizeof(int), stream);
    k_hist<<<NB_E, 256, 0, stream>>>(dst, cnt, E);
    k_dis<<<NB_N, 256, 0, stream>>>(cnt, dis, N);
    k_bktcnt<<<NB_BK, 256, 0, stream>>>(cnt, bktTotal, N, NBKT);
    k_bktscan<<<1, 512, 0, stream>>>(bktTotal, bktStart, cursorB, NBKT);
    k_part<<<NB_PT, 256, 0, stream>>>(src, dst, dis, cursorB, tmp, E, NBKT);

    // ---- layer 1 ----
    k_mmrt<IN_DIM><<<NB_MM, 256, 0, stream>>>(x, W1, bufA, N);
    k_agg<<<NBKT, 256, 0, stream>>>(bufA, tmp, bktStart, dis, b1, bufB, N);

    // ---- layer 2 ----
    k_mmrt<HID><<<NB_MM, 256, 0, stream>>>(bufB, W2, bufA, N);
    k_agg<<<NBKT, 256, 0, stream>>>(bufA, tmp, bktStart, dis, b2, bufB, N);

    // ---- layer 3 (OUT_DIM = 1) ----
    k_mm1col<<<NB_WV, 256, 0, stream>>>(bufB, W3, col, N);
    k_agg1<<<NBKT, 256, 0, stream>>>(col, tmp, bktStart, dis, b3, out, N);
}

// Round 5
// 416.252 us; speedup vs baseline: 3.6927x; 3.6927x over previous
//
#include <hip/hip_runtime.h>

#define IN_DIM 128
#define HID 64
#define MAXC 400            // >= ceil(N/256); N=100000 -> 391 coarse buckets
#define EPB 8192

// ---------------- per-node degree histogram ----------------
__global__ __launch_bounds__(256) void k_hist(const int* __restrict__ dst,
                                              int* __restrict__ cnt, int E) {
    int e = blockIdx.x * 256 + threadIdx.x;
    if (e < E) atomicAdd(&cnt[dst[e]], 1);
}

// ---------------- dis = rsqrt(1 + deg) ----------------
__global__ __launch_bounds__(256) void k_dis(const int* __restrict__ cnt,
                                             float* __restrict__ dis, int N) {
    int i = blockIdx.x * 256 + threadIdx.x;
    if (i < N) dis[i] = rsqrtf((float)cnt[i] + 1.0f);
}

// ---------------- exclusive scan over nodes (3-kernel classic) ----------------
__global__ __launch_bounds__(256) void k_scan_block(const int* __restrict__ cnt,
                                                    int* __restrict__ partial,
                                                    int* __restrict__ blockSums, int N) {
    __shared__ int tmp[256];
    int i = blockIdx.x * 256 + threadIdx.x;
    int v = (i < N) ? cnt[i] : 0;
    tmp[threadIdx.x] = v;
    __syncthreads();
    for (int off = 1; off < 256; off <<= 1) {
        int t = (threadIdx.x >= off) ? tmp[threadIdx.x - off] : 0;
        __syncthreads();
        tmp[threadIdx.x] += t;
        __syncthreads();
    }
    int incl = tmp[threadIdx.x];
    if (i < N) partial[i] = incl - v;           // exclusive
    if (threadIdx.x == 255) blockSums[blockIdx.x] = incl;
}

__global__ __launch_bounds__(512) void k_scan_sums(int* __restrict__ blockSums, int nB) {
    __shared__ int tmp[512];
    int t = threadIdx.x;
    int v = (t < nB) ? blockSums[t] : 0;
    tmp[t] = v;
    __syncthreads();
    for (int off = 1; off < 512; off <<= 1) {
        int a = (t >= off) ? tmp[t - off] : 0;
        __syncthreads();
        tmp[t] += a;
        __syncthreads();
    }
    int incl = tmp[t];
    __syncthreads();
    if (t < nB) blockSums[t] = incl - v;        // exclusive, in place
}

// also seeds the coarse-bucket cursors: cursorC[cb] = rowStart[cb*256]
__global__ __launch_bounds__(256) void k_scan_add(const int* __restrict__ partial,
                                                  const int* __restrict__ blockOff,
                                                  int* __restrict__ rowStart,
                                                  int* __restrict__ cursorC, int N, int E) {
    int i = blockIdx.x * 256 + threadIdx.x;
    if (i < N) {
        int rs = partial[i] + blockOff[i >> 8];
        rowStart[i] = rs;
        if ((i & 255) == 0) cursorC[i >> 8] = rs;
    } else if (i == N) {
        rowStart[N] = E;
    }
}

// ---------------- pass 1: partition edges into coarse buckets (256 dst nodes) ----------
// tmp1[pos] = { src | (dloc<<17), norm }, dloc = dst & 255
__global__ __launch_bounds__(256) void k_part1(const int* __restrict__ src,
                                               const int* __restrict__ dst,
                                               const float* __restrict__ dis,
                                               int* __restrict__ cursorC,
                                               int2* __restrict__ tmp1,
                                               int E, int NC) {
    __shared__ int bcnt[MAXC];
    __shared__ int bbase[MAXC];
    int tid = threadIdx.x;
    int e0 = blockIdx.x * EPB;
    int e1 = min(e0 + EPB, E);
    for (int i = tid; i < NC; i += 256) bcnt[i] = 0;
    __syncthreads();
    for (int e = e0 + tid; e < e1; e += 256) atomicAdd(&bcnt[dst[e] >> 8], 1);
    __syncthreads();
    for (int i = tid; i < NC; i += 256) {
        int c = bcnt[i];
        bbase[i] = c ? atomicAdd(&cursorC[i], c) : 0;
    }
    __syncthreads();
    for (int i = tid; i < NC; i += 256) bcnt[i] = 0;
    __syncthreads();
    for (int e = e0 + tid; e < e1; e += 256) {
        int s = src[e], d = dst[e];
        int cb = d >> 8;
        int slot = bbase[cb] + atomicAdd(&bcnt[cb], 1);
        int2 pk;
        pk.x = s | ((d & 255) << 17);
        pk.y = __float_as_int(dis[s] * dis[d]);
        tmp1[slot] = pk;    // ~170B contiguous runs per (block, bucket)
    }
}

// ---------------- pass 2: within coarse bucket, place to exact CSR slot -------------
// writes land in a ~33KB window -> L2-resident, full-line dirty
__global__ __launch_bounds__(256) void k_part2(const int2* __restrict__ tmp1,
                                               const int* __restrict__ rowStart,
                                               int2* __restrict__ epk, int N) {
    __shared__ int cur[256];
    int tid = threadIdx.x;
    int node0 = blockIdx.x << 8;
    int nodes = min(256, N - node0);
    if (tid < nodes) cur[tid] = rowStart[node0 + tid];
    __syncthreads();
    int r0 = rowStart[node0];
    int r1 = rowStart[node0 + nodes];
    for (int e = r0 + tid; e < r1; e += 256) {
        int2 pk = tmp1[e];
        int dl = pk.x >> 17;
        int pos = atomicAdd(&cur[dl], 1);
        epk[pos] = make_int2(pk.x & 0x1FFFF, pk.y);
    }
}

// ---------------- register-tiled transform: H[N,64] = X[N,K] @ W[K,64] ----------------
template <int K>
__global__ __launch_bounds__(256) void k_mmrt(const float* __restrict__ X,
                                              const float* __restrict__ W,
                                              float* __restrict__ H, int N) {
    constexpr int BR = 128, BK = 32, S = 132;
    __shared__ float Xs[BK * S];
    __shared__ float Ws[BK * 64];
    const int tid = threadIdx.x;
    const int c0 = (tid & 15) * 4;
    const int row0 = (tid >> 4) * 8;
    const int blockRow = blockIdx.x * BR;
    float acc[8][4];
#pragma unroll
    for (int r = 0; r < 8; ++r)
#pragma unroll
        for (int c = 0; c < 4; ++c) acc[r][c] = 0.f;

    for (int k0 = 0; k0 < K; k0 += BK) {
        int i = tid;
#pragma unroll
        for (int it = 0; it < 4; ++it, i += 256) {
            int row = i >> 3, kq = i & 7;
            int gr = blockRow + row;
            if (gr >= N) gr = N - 1;
            float4 v = *(const float4*)&X[(size_t)gr * K + k0 + kq * 4];
            Xs[(kq * 4 + 0) * S + row] = v.x;
            Xs[(kq * 4 + 1) * S + row] = v.y;
            Xs[(kq * 4 + 2) * S + row] = v.z;
            Xs[(kq * 4 + 3) * S + row] = v.w;
        }
        int j2 = tid;
#pragma unroll
        for (int it = 0; it < 2; ++it, j2 += 256) {
            int k = j2 >> 4, cq = j2 & 15;
            *(float4*)&Ws[k * 64 + cq * 4] =
                *(const float4*)&W[(size_t)(k0 + k) * 64 + cq * 4];
        }
        __syncthreads();
#pragma unroll
        for (int kk = 0; kk < BK; kk += 4) {
            float4 b[4], alo[4], ahi[4];
#pragma unroll
            for (int j = 0; j < 4; ++j) {
                b[j]   = *(const float4*)&Ws[(kk + j) * 64 + c0];
                alo[j] = *(const float4*)&Xs[(kk + j) * S + row0];
                ahi[j] = *(const float4*)&Xs[(kk + j) * S + row0 + 4];
            }
#pragma unroll
            for (int j = 0; j < 4; ++j) {
                const float a_[8] = {alo[j].x, alo[j].y, alo[j].z, alo[j].w,
                                     ahi[j].x, ahi[j].y, ahi[j].z, ahi[j].w};
#pragma unroll
                for (int r = 0; r < 8; ++r) {
                    acc[r][0] += a_[r] * b[j].x;
                    acc[r][1] += a_[r] * b[j].y;
                    acc[r][2] += a_[r] * b[j].z;
                    acc[r][3] += a_[r] * b[j].w;
                }
            }
        }
        __syncthreads();
    }
#pragma unroll
    for (int r = 0; r < 8; ++r) {
        int gr = blockRow + row0 + r;
        if (gr < N) *(float4*)&H[(size_t)gr * 64 + c0] = *(float4*)&acc[r][0];
    }
}

// ---------------- gather-aggregate: wave per node, lane = feature ----------------
__global__ __launch_bounds__(256) void k_gather64(const float* __restrict__ H,
                                                  const int2* __restrict__ epk,
                                                  const int* __restrict__ rowStart,
                                                  const float* __restrict__ dis,
                                                  const float* __restrict__ b,
                                                  float* __restrict__ out,
                                                  int N, int doRelu) {
    int lane = threadIdx.x & 63;
    int node = (blockIdx.x * 256 + threadIdx.x) >> 6;
    if (node >= N) return;
    int r0 = rowStart[node], r1 = rowStart[node + 1];
    float d = dis[node];
    float acc = H[(size_t)node * 64 + lane] * d * d + b[lane];

    for (int base = r0; base < r1; base += 64) {
        int cnt = min(64, r1 - base);
        int2 pk = (lane < cnt) ? epk[base + lane] : make_int2(0, 0);
        int s = pk.x;
        float nm = __int_as_float(pk.y);
        int j = 0;
        for (; j + 4 <= cnt; j += 4) {
            int s0 = __shfl(s, j, 64),     s1 = __shfl(s, j + 1, 64);
            int s2 = __shfl(s, j + 2, 64), s3 = __shfl(s, j + 3, 64);
            float n0 = __shfl(nm, j, 64),     n1 = __shfl(nm, j + 1, 64);
            float n2 = __shfl(nm, j + 2, 64), n3 = __shfl(nm, j + 3, 64);
            float h0 = H[(size_t)s0 * 64 + lane];
            float h1 = H[(size_t)s1 * 64 + lane];
            float h2 = H[(size_t)s2 * 64 + lane];
            float h3 = H[(size_t)s3 * 64 + lane];
            acc += h0 * n0;
            acc += h1 * n1;
            acc += h2 * n2;
            acc += h3 * n3;
        }
        for (; j < cnt; ++j) {
            int sj = __shfl(s, j, 64);
            float nj = __shfl(nm, j, 64);
            acc += H[(size_t)sj * 64 + lane] * nj;
        }
    }
    if (doRelu) acc = fmaxf(acc, 0.0f);
    out[(size_t)node * 64 + lane] = acc;
}

// ---------------- layer 3: col[i] = H[i,:]·W3 ; out[i] = col*dis^2 + b3 ----------------
__global__ __launch_bounds__(256) void k_mm1col(const float* __restrict__ H,
                                                const float* __restrict__ W3,
                                                const float* __restrict__ b3,
                                                const float* __restrict__ dis,
                                                float* __restrict__ col,
                                                float* __restrict__ out, int N) {
    int lane = threadIdx.x & 63;
    int node = (blockIdx.x * 256 + threadIdx.x) >> 6;
    if (node >= N) return;
    float v = H[(size_t)node * 64 + lane] * W3[lane];
#pragma unroll
    for (int off = 32; off >= 1; off >>= 1) v += __shfl_down(v, off, 64);
    if (lane == 0) {
        float d = dis[node];
        col[node] = v;
        out[node] = v * d * d + b3[0];
    }
}

__global__ __launch_bounds__(256) void k_gather1(const float* __restrict__ col,
                                                 const int2* __restrict__ epk,
                                                 const int* __restrict__ rowStart,
                                                 float* __restrict__ out, int N) {
    int i = blockIdx.x * 256 + threadIdx.x;
    if (i >= N) return;
    int r0 = rowStart[i], r1 = rowStart[i + 1];
    float acc = 0.0f;
    for (int e = r0; e < r1; ++e) {
        int2 pk = epk[e];
        acc += col[pk.x] * __int_as_float(pk.y);
    }
    out[i] += acc;
}

extern "C" void kernel_launch(void* const* d_in, const int* in_sizes, int n_in,
                              void* d_out, int out_size, void* d_ws, size_t ws_size,
                              hipStream_t stream) {
    const float* x  = (const float*)d_in[0];
    const int*   ei = (const int*)d_in[1];
    const float* W1 = (const float*)d_in[2];
    const float* b1 = (const float*)d_in[3];
    const float* W2 = (const float*)d_in[4];
    const float* b2 = (const float*)d_in[5];
    const float* W3 = (const float*)d_in[6];
    const float* b3 = (const float*)d_in[7];
    float* out = (float*)d_out;

    const int N = in_sizes[0] / IN_DIM;     // 100000
    const int E = in_sizes[1] / 2;          // 1600000
    const int* src = ei;
    const int* dst = ei + E;
    const int NC = (N + 255) >> 8;          // 391 coarse buckets

    // ---- workspace layout ----
    char* w = (char*)d_ws;
    auto alloc = [&](size_t bytes) {
        char* p = w;
        w += (bytes + 1023) & ~(size_t)1023;
        return p;
    };
    float* dis      = (float*)alloc((size_t)N * 4);
    float* bufA     = (float*)alloc((size_t)N * 64 * 4);
    float* bufB     = (float*)alloc((size_t)N * 64 * 4);
    float* col      = (float*)alloc((size_t)N * 4);
    int*   cnt      = (int*)alloc((size_t)N * 4);
    int*   partial  = (int*)alloc((size_t)N * 4);
    int*   rowStart = (int*)alloc((size_t)(N + 1) * 4);
    int*   cursorC  = (int*)alloc((size_t)MAXC * 4);
    int*   blockSums= (int*)alloc((size_t)512 * 4);
    int2*  epk      = (int2*)alloc((size_t)E * 8);
    int2*  tmp1     = (int2*)bufA;          // aliased: dead before first k_mmrt

    const int NB_N  = (N + 255) / 256;
    const int NB_N1 = (N + 1 + 255) / 256;
    const int NB_E  = (E + 255) / 256;
    const int NB_MM = (N + 127) / 128;
    const int NB_WV = (N * 64 + 255) / 256;
    const int NB_P1 = (E + EPB - 1) / EPB;
    const int nB    = NB_N;

    // ---- degree + two-pass CSR build ----
    hipMemsetAsync(cnt, 0, (size_t)N * sizeof(int), stream);
    k_hist<<<NB_E, 256, 0, stream>>>(dst, cnt, E);
    k_dis<<<NB_N, 256, 0, stream>>>(cnt, dis, N);
    k_scan_block<<<nB, 256, 0, stream>>>(cnt, partial, blockSums, N);
    k_scan_sums<<<1, 512, 0, stream>>>(blockSums, nB);
    k_scan_add<<<NB_N1, 256, 0, stream>>>(partial, blockSums, rowStart, cursorC, N, E);
    k_part1<<<NB_P1, 256, 0, stream>>>(src, dst, dis, cursorC, tmp1, E, NC);
    k_part2<<<NC, 256, 0, stream>>>(tmp1, rowStart, epk, N);

    // ---- layer 1 ----
    k_mmrt<IN_DIM><<<NB_MM, 256, 0, stream>>>(x, W1, bufA, N);
    k_gather64<<<NB_WV, 256, 0, stream>>>(bufA, epk, rowStart, dis, b1, bufB, N, 1);

    // ---- layer 2 ----
    k_mmrt<HID><<<NB_MM, 256, 0, stream>>>(bufB, W2, bufA, N);
    k_gather64<<<NB_WV, 256, 0, stream>>>(bufA, epk, rowStart, dis, b2, bufB, N, 1);

    // ---- layer 3 (OUT_DIM = 1) ----
    k_mm1col<<<NB_WV, 256, 0, stream>>>(bufB, W3, b3, dis, col, out, N);
    k_gather1<<<NB_N, 256, 0, stream>>>(col, epk, rowStart, out, N);
}

// Round 6
// 352.451 us; speedup vs baseline: 4.3612x; 1.1810x over previous
//
#include <hip/hip_runtime.h>

#define IN_DIM 128
#define HID 64
#define MAXC 400            // >= ceil(N/256); N=100000 -> 391 coarse buckets
#define EPB 8192

// ---------------- coarse histogram: LDS-privatized, tiny global merge ----------------
__global__ __launch_bounds__(256) void k_coarse(const int* __restrict__ dst,
                                                int* __restrict__ coarseCnt,
                                                int E, int NC) {
    __shared__ int h[MAXC];
    int tid = threadIdx.x;
    for (int i = tid; i < NC; i += 256) h[i] = 0;
    __syncthreads();
    int e0 = blockIdx.x * EPB, e1 = min(e0 + EPB, E);
    for (int e = e0 + tid; e < e1; e += 256) atomicAdd(&h[dst[e] >> 8], 1);
    __syncthreads();
    for (int i = tid; i < NC; i += 256)
        if (h[i]) atomicAdd(&coarseCnt[i], h[i]);
}

// ---------------- single-block scan over coarse buckets ----------------
__global__ __launch_bounds__(512) void k_cscan(const int* __restrict__ coarseCnt,
                                               int* __restrict__ coarseStart,
                                               int* __restrict__ cursorC,
                                               int* __restrict__ rowStart,
                                               int NC, int N, int E) {
    __shared__ int tmp[512];
    int t = threadIdx.x;
    int v = (t < NC) ? coarseCnt[t] : 0;
    tmp[t] = v;
    __syncthreads();
    for (int off = 1; off < 512; off <<= 1) {
        int a = (t >= off) ? tmp[t - off] : 0;
        __syncthreads();
        tmp[t] += a;
        __syncthreads();
    }
    int excl = tmp[t] - v;
    if (t < NC) { coarseStart[t] = excl; cursorC[t] = excl; }
    if (t == NC - 1) coarseStart[NC] = excl + v;   // == E
    if (t == 0) rowStart[N] = E;
}

// ---------------- pass 1: partition into coarse buckets, 4B payload ----------------
// tmp1[pos] = src | (dloc << 17), dloc = dst & 255
__global__ __launch_bounds__(256) void k_part1(const int* __restrict__ src,
                                               const int* __restrict__ dst,
                                               int* __restrict__ cursorC,
                                               int* __restrict__ tmp1,
                                               int E, int NC) {
    __shared__ int bcnt[MAXC];
    __shared__ int bbase[MAXC];
    int tid = threadIdx.x;
    int e0 = blockIdx.x * EPB;
    int e1 = min(e0 + EPB, E);
    for (int i = tid; i < NC; i += 256) bcnt[i] = 0;
    __syncthreads();
    for (int e = e0 + tid; e < e1; e += 256) atomicAdd(&bcnt[dst[e] >> 8], 1);
    __syncthreads();
    for (int i = tid; i < NC; i += 256) {
        int c = bcnt[i];
        bbase[i] = c ? atomicAdd(&cursorC[i], c) : 0;
    }
    __syncthreads();
    for (int i = tid; i < NC; i += 256) bcnt[i] = 0;
    __syncthreads();
    for (int e = e0 + tid; e < e1; e += 256) {
        int s = src[e], d = dst[e];
        int cb = d >> 8;
        int slot = bbase[cb] + atomicAdd(&bcnt[cb], 1);
        tmp1[slot] = s | ((d & 255) << 17);
    }
}

// ---------------- pass 2a: per-bucket degree histogram -> dis + rowStart ----------------
__global__ __launch_bounds__(256) void k_deg(const int* __restrict__ tmp1,
                                             const int* __restrict__ coarseStart,
                                             float* __restrict__ dis,
                                             int* __restrict__ rowStart, int N) {
    __shared__ int hist[256];
    __shared__ int scn[256];
    int tid = threadIdx.x;
    int cb = blockIdx.x;
    int node0 = cb << 8;
    hist[tid] = 0;
    __syncthreads();
    int r0 = coarseStart[cb], r1 = coarseStart[cb + 1];
    for (int e = r0 + tid; e < r1; e += 256)
        atomicAdd(&hist[((unsigned)tmp1[e]) >> 17], 1);
    __syncthreads();
    int v = hist[tid];
    scn[tid] = v;
    __syncthreads();
    for (int off = 1; off < 256; off <<= 1) {
        int a = (tid >= off) ? scn[tid - off] : 0;
        __syncthreads();
        scn[tid] += a;
        __syncthreads();
    }
    int node = node0 + tid;
    if (node < N) {
        dis[node] = rsqrtf((float)v + 1.0f);
        rowStart[node] = r0 + scn[tid] - v;     // exclusive within bucket + base
    }
}

// ---------------- pass 2b: place edges to CSR slots with norm ----------------
__global__ __launch_bounds__(256) void k_place(const int* __restrict__ tmp1,
                                               const int* __restrict__ coarseStart,
                                               const int* __restrict__ rowStart,
                                               const float* __restrict__ dis,
                                               int2* __restrict__ epk, int N) {
    __shared__ int cur[256];
    __shared__ float dld[256];
    int tid = threadIdx.x;
    int cb = blockIdx.x;
    int node = (cb << 8) + tid;
    cur[tid] = (node < N) ? rowStart[node] : 0;
    dld[tid] = (node < N) ? dis[node] : 0.f;
    __syncthreads();
    int r0 = coarseStart[cb], r1 = coarseStart[cb + 1];
    for (int e = r0 + tid; e < r1; e += 256) {
        int v = tmp1[e];
        int s = v & 0x1FFFF;
        int dl = ((unsigned)v) >> 17;
        float nm = dis[s] * dld[dl];
        int pos = atomicAdd(&cur[dl], 1);
        epk[pos] = make_int2(s, __float_as_int(nm));
    }
}

// ---------------- register-tiled transform: H[N,64] = X[N,K] @ W[K,64] ----------------
template <int K>
__global__ __launch_bounds__(256) void k_mmrt(const float* __restrict__ X,
                                              const float* __restrict__ W,
                                              float* __restrict__ H, int N) {
    constexpr int BR = 128, BK = 32, S = 132;
    __shared__ float Xs[BK * S];
    __shared__ float Ws[BK * 64];
    const int tid = threadIdx.x;
    const int c0 = (tid & 15) * 4;
    const int row0 = (tid >> 4) * 8;
    const int blockRow = blockIdx.x * BR;
    float acc[8][4];
#pragma unroll
    for (int r = 0; r < 8; ++r)
#pragma unroll
        for (int c = 0; c < 4; ++c) acc[r][c] = 0.f;

    for (int k0 = 0; k0 < K; k0 += BK) {
        int i = tid;
#pragma unroll
        for (int it = 0; it < 4; ++it, i += 256) {
            int row = i >> 3, kq = i & 7;
            int gr = blockRow + row;
            if (gr >= N) gr = N - 1;
            float4 v = *(const float4*)&X[(size_t)gr * K + k0 + kq * 4];
            Xs[(kq * 4 + 0) * S + row] = v.x;
            Xs[(kq * 4 + 1) * S + row] = v.y;
            Xs[(kq * 4 + 2) * S + row] = v.z;
            Xs[(kq * 4 + 3) * S + row] = v.w;
        }
        int j2 = tid;
#pragma unroll
        for (int it = 0; it < 2; ++it, j2 += 256) {
            int k = j2 >> 4, cq = j2 & 15;
            *(float4*)&Ws[k * 64 + cq * 4] =
                *(const float4*)&W[(size_t)(k0 + k) * 64 + cq * 4];
        }
        __syncthreads();
#pragma unroll
        for (int kk = 0; kk < BK; kk += 4) {
            float4 b[4], alo[4], ahi[4];
#pragma unroll
            for (int j = 0; j < 4; ++j) {
                b[j]   = *(const float4*)&Ws[(kk + j) * 64 + c0];
                alo[j] = *(const float4*)&Xs[(kk + j) * S + row0];
                ahi[j] = *(const float4*)&Xs[(kk + j) * S + row0 + 4];
            }
#pragma unroll
            for (int j = 0; j < 4; ++j) {
                const float a_[8] = {alo[j].x, alo[j].y, alo[j].z, alo[j].w,
                                     ahi[j].x, ahi[j].y, ahi[j].z, ahi[j].w};
#pragma unroll
                for (int r = 0; r < 8; ++r) {
                    acc[r][0] += a_[r] * b[j].x;
                    acc[r][1] += a_[r] * b[j].y;
                    acc[r][2] += a_[r] * b[j].z;
                    acc[r][3] += a_[r] * b[j].w;
                }
            }
        }
        __syncthreads();
    }
#pragma unroll
    for (int r = 0; r < 8; ++r) {
        int gr = blockRow + row0 + r;
        if (gr < N) *(float4*)&H[(size_t)gr * 64 + c0] = *(float4*)&acc[r][0];
    }
}

// ---------------- gather-aggregate: wave per node, lane = feature ----------------
__global__ __launch_bounds__(256) void k_gather64(const float* __restrict__ H,
                                                  const int2* __restrict__ epk,
                                                  const int* __restrict__ rowStart,
                                                  const float* __restrict__ dis,
                                                  const float* __restrict__ b,
                                                  float* __restrict__ out,
                                                  int N, int doRelu) {
    int lane = threadIdx.x & 63;
    int node = (blockIdx.x * 256 + threadIdx.x) >> 6;
    if (node >= N) return;
    int r0 = rowStart[node], r1 = rowStart[node + 1];
    float d = dis[node];
    float acc = H[(size_t)node * 64 + lane] * d * d + b[lane];

    for (int base = r0; base < r1; base += 64) {
        int cnt = min(64, r1 - base);
        int2 pk = (lane < cnt) ? epk[base + lane] : make_int2(0, 0);
        int s = pk.x;
        float nm = __int_as_float(pk.y);
        int j = 0;
        for (; j + 4 <= cnt; j += 4) {
            int s0 = __shfl(s, j, 64),     s1 = __shfl(s, j + 1, 64);
            int s2 = __shfl(s, j + 2, 64), s3 = __shfl(s, j + 3, 64);
            float n0 = __shfl(nm, j, 64),     n1 = __shfl(nm, j + 1, 64);
            float n2 = __shfl(nm, j + 2, 64), n3 = __shfl(nm, j + 3, 64);
            float h0 = H[(size_t)s0 * 64 + lane];
            float h1 = H[(size_t)s1 * 64 + lane];
            float h2 = H[(size_t)s2 * 64 + lane];
            float h3 = H[(size_t)s3 * 64 + lane];
            acc += h0 * n0;
            acc += h1 * n1;
            acc += h2 * n2;
            acc += h3 * n3;
        }
        for (; j < cnt; ++j) {
            int sj = __shfl(s, j, 64);
            float nj = __shfl(nm, j, 64);
            acc += H[(size_t)sj * 64 + lane] * nj;
        }
    }
    if (doRelu) acc = fmaxf(acc, 0.0f);
    out[(size_t)node * 64 + lane] = acc;
}

// ---------------- layer 3 ----------------
__global__ __launch_bounds__(256) void k_mm1col(const float* __restrict__ H,
                                                const float* __restrict__ W3,
                                                const float* __restrict__ b3,
                                                const float* __restrict__ dis,
                                                float* __restrict__ col,
                                                float* __restrict__ out, int N) {
    int lane = threadIdx.x & 63;
    int node = (blockIdx.x * 256 + threadIdx.x) >> 6;
    if (node >= N) return;
    float v = H[(size_t)node * 64 + lane] * W3[lane];
#pragma unroll
    for (int off = 32; off >= 1; off >>= 1) v += __shfl_down(v, off, 64);
    if (lane == 0) {
        float d = dis[node];
        col[node] = v;
        out[node] = v * d * d + b3[0];
    }
}

__global__ __launch_bounds__(256) void k_gather1(const float* __restrict__ col,
                                                 const int2* __restrict__ epk,
                                                 const int* __restrict__ rowStart,
                                                 float* __restrict__ out, int N) {
    int i = blockIdx.x * 256 + threadIdx.x;
    if (i >= N) return;
    int r0 = rowStart[i], r1 = rowStart[i + 1];
    float acc = 0.0f;
    for (int e = r0; e < r1; ++e) {
        int2 pk = epk[e];
        acc += col[pk.x] * __int_as_float(pk.y);
    }
    out[i] += acc;
}

extern "C" void kernel_launch(void* const* d_in, const int* in_sizes, int n_in,
                              void* d_out, int out_size, void* d_ws, size_t ws_size,
                              hipStream_t stream) {
    const float* x  = (const float*)d_in[0];
    const int*   ei = (const int*)d_in[1];
    const float* W1 = (const float*)d_in[2];
    const float* b1 = (const float*)d_in[3];
    const float* W2 = (const float*)d_in[4];
    const float* b2 = (const float*)d_in[5];
    const float* W3 = (const float*)d_in[6];
    const float* b3 = (const float*)d_in[7];
    float* out = (float*)d_out;

    const int N = in_sizes[0] / IN_DIM;     // 100000
    const int E = in_sizes[1] / 2;          // 1600000
    const int* src = ei;
    const int* dst = ei + E;
    const int NC = (N + 255) >> 8;          // 391 coarse buckets

    // ---- workspace layout ----
    char* w = (char*)d_ws;
    auto alloc = [&](size_t bytes) {
        char* p = w;
        w += (bytes + 1023) & ~(size_t)1023;
        return p;
    };
    float* dis        = (float*)alloc((size_t)N * 4);
    float* bufA       = (float*)alloc((size_t)N * 64 * 4);
    float* bufB       = (float*)alloc((size_t)N * 64 * 4);
    float* col        = (float*)alloc((size_t)N * 4);
    int*   rowStart   = (int*)alloc((size_t)(N + 1) * 4);
    int*   coarseCnt  = (int*)alloc((size_t)MAXC * 4);
    int*   coarseStart= (int*)alloc((size_t)(MAXC + 1) * 4);
    int*   cursorC    = (int*)alloc((size_t)MAXC * 4);
    int2*  epk        = (int2*)alloc((size_t)E * 8);
    int*   tmp1       = (int*)bufA;         // aliased: dead before first k_mmrt

    const int NB_N  = (N + 255) / 256;
    const int NB_MM = (N + 127) / 128;
    const int NB_WV = (N * 64 + 255) / 256;
    const int NB_P  = (E + EPB - 1) / EPB;

    // ---- partition-driven CSR + degrees ----
    hipMemsetAsync(coarseCnt, 0, (size_t)MAXC * sizeof(int), stream);
    k_coarse<<<NB_P, 256, 0, stream>>>(dst, coarseCnt, E, NC);
    k_cscan<<<1, 512, 0, stream>>>(coarseCnt, coarseStart, cursorC, rowStart, NC, N, E);
    k_part1<<<NB_P, 256, 0, stream>>>(src, dst, cursorC, tmp1, E, NC);
    k_deg<<<NC, 256, 0, stream>>>(tmp1, coarseStart, dis, rowStart, N);
    k_place<<<NC, 256, 0, stream>>>(tmp1, coarseStart, rowStart, dis, epk, N);

    // ---- layer 1 ----
    k_mmrt<IN_DIM><<<NB_MM, 256, 0, stream>>>(x, W1, bufA, N);
    k_gather64<<<NB_WV, 256, 0, stream>>>(bufA, epk, rowStart, dis, b1, bufB, N, 1);

    // ---- layer 2 ----
    k_mmrt<HID><<<NB_MM, 256, 0, stream>>>(bufB, W2, bufA, N);
    k_gather64<<<NB_WV, 256, 0, stream>>>(bufA, epk, rowStart, dis, b2, bufB, N, 1);

    // ---- layer 3 (OUT_DIM = 1) ----
    k_mm1col<<<NB_WV, 256, 0, stream>>>(bufB, W3, b3, dis, col, out, N);
    k_gather1<<<NB_N, 256, 0, stream>>>(col, epk, rowStart, out, N);
}

// Round 7
// 335.542 us; speedup vs baseline: 4.5810x; 1.0504x over previous
//
#include <hip/hip_runtime.h>

#define IN_DIM 128
#define HID 64
#define MAXC 400            // >= ceil(N/256); N=100000 -> 391 coarse buckets
#define EPB 8192

// ---- bf16 helpers (RNE) ----
static __device__ __forceinline__ unsigned short f2bf(float f) {
    unsigned u = __float_as_uint(f);
    u += 0x7FFF + ((u >> 16) & 1);
    return (unsigned short)(u >> 16);
}
static __device__ __forceinline__ float bf2f(unsigned short h) {
    return __uint_as_float((unsigned)h << 16);
}

// ---------------- coarse histogram: LDS-privatized, tiny global merge ----------------
__global__ __launch_bounds__(256) void k_coarse(const int* __restrict__ dst,
                                                int* __restrict__ coarseCnt,
                                                int E, int NC) {
    __shared__ int h[MAXC];
    int tid = threadIdx.x;
    for (int i = tid; i < NC; i += 256) h[i] = 0;
    __syncthreads();
    int e0 = blockIdx.x * EPB, e1 = min(e0 + EPB, E);
    for (int e = e0 + tid; e < e1; e += 256) atomicAdd(&h[dst[e] >> 8], 1);
    __syncthreads();
    for (int i = tid; i < NC; i += 256)
        if (h[i]) atomicAdd(&coarseCnt[i], h[i]);
}

// ---------------- single-block scan over coarse buckets ----------------
__global__ __launch_bounds__(512) void k_cscan(const int* __restrict__ coarseCnt,
                                               int* __restrict__ coarseStart,
                                               int* __restrict__ cursorC,
                                               int* __restrict__ rowStart,
                                               int NC, int N, int E) {
    __shared__ int tmp[512];
    int t = threadIdx.x;
    int v = (t < NC) ? coarseCnt[t] : 0;
    tmp[t] = v;
    __syncthreads();
    for (int off = 1; off < 512; off <<= 1) {
        int a = (t >= off) ? tmp[t - off] : 0;
        __syncthreads();
        tmp[t] += a;
        __syncthreads();
    }
    int excl = tmp[t] - v;
    if (t < NC) { coarseStart[t] = excl; cursorC[t] = excl; }
    if (t == NC - 1) coarseStart[NC] = excl + v;   // == E
    if (t == 0) rowStart[N] = E;
}

// ---------------- pass 1: partition into coarse buckets, 4B payload ----------------
__global__ __launch_bounds__(256) void k_part1(const int* __restrict__ src,
                                               const int* __restrict__ dst,
                                               int* __restrict__ cursorC,
                                               int* __restrict__ tmp1,
                                               int E, int NC) {
    __shared__ int bcnt[MAXC];
    __shared__ int bbase[MAXC];
    int tid = threadIdx.x;
    int e0 = blockIdx.x * EPB;
    int e1 = min(e0 + EPB, E);
    for (int i = tid; i < NC; i += 256) bcnt[i] = 0;
    __syncthreads();
    for (int e = e0 + tid; e < e1; e += 256) atomicAdd(&bcnt[dst[e] >> 8], 1);
    __syncthreads();
    for (int i = tid; i < NC; i += 256) {
        int c = bcnt[i];
        bbase[i] = c ? atomicAdd(&cursorC[i], c) : 0;
    }
    __syncthreads();
    for (int i = tid; i < NC; i += 256) bcnt[i] = 0;
    __syncthreads();
    for (int e = e0 + tid; e < e1; e += 256) {
        int s = src[e], d = dst[e];
        int cb = d >> 8;
        int slot = bbase[cb] + atomicAdd(&bcnt[cb], 1);
        tmp1[slot] = s | ((d & 255) << 17);
    }
}

// ---------------- pass 2a: per-bucket degree histogram -> dis + rowStart ----------------
__global__ __launch_bounds__(256) void k_deg(const int* __restrict__ tmp1,
                                             const int* __restrict__ coarseStart,
                                             float* __restrict__ dis,
                                             int* __restrict__ rowStart, int N) {
    __shared__ int hist[256];
    __shared__ int scn[256];
    int tid = threadIdx.x;
    int cb = blockIdx.x;
    int node0 = cb << 8;
    hist[tid] = 0;
    __syncthreads();
    int r0 = coarseStart[cb], r1 = coarseStart[cb + 1];
    for (int e = r0 + tid; e < r1; e += 256)
        atomicAdd(&hist[((unsigned)tmp1[e]) >> 17], 1);
    __syncthreads();
    int v = hist[tid];
    scn[tid] = v;
    __syncthreads();
    for (int off = 1; off < 256; off <<= 1) {
        int a = (tid >= off) ? scn[tid - off] : 0;
        __syncthreads();
        scn[tid] += a;
        __syncthreads();
    }
    int node = node0 + tid;
    if (node < N) {
        dis[node] = rsqrtf((float)v + 1.0f);
        rowStart[node] = r0 + scn[tid] - v;
    }
}

// ---------------- pass 2b: place edges to CSR slots with norm ----------------
__global__ __launch_bounds__(256) void k_place(const int* __restrict__ tmp1,
                                               const int* __restrict__ coarseStart,
                                               const int* __restrict__ rowStart,
                                               const float* __restrict__ dis,
                                               int2* __restrict__ epk, int N) {
    __shared__ int cur[256];
    __shared__ float dld[256];
    int tid = threadIdx.x;
    int cb = blockIdx.x;
    int node = (cb << 8) + tid;
    cur[tid] = (node < N) ? rowStart[node] : 0;
    dld[tid] = (node < N) ? dis[node] : 0.f;
    __syncthreads();
    int r0 = coarseStart[cb], r1 = coarseStart[cb + 1];
    for (int e = r0 + tid; e < r1; e += 256) {
        int v = tmp1[e];
        int s = v & 0x1FFFF;
        int dl = ((unsigned)v) >> 17;
        float nm = dis[s] * dld[dl];
        int pos = atomicAdd(&cur[dl], 1);
        epk[pos] = make_int2(s, __float_as_int(nm));
    }
}

// ---------------- register-tiled transform: H = X @ W, dual fp32 + bf16 output ------
template <int K>
__global__ __launch_bounds__(256) void k_mmrt(const float* __restrict__ X,
                                              const float* __restrict__ W,
                                              float* __restrict__ H,
                                              unsigned short* __restrict__ Hb, int N) {
    constexpr int BR = 128, BK = 32, S = 132;
    __shared__ float Xs[BK * S];
    __shared__ float Ws[BK * 64];
    const int tid = threadIdx.x;
    const int c0 = (tid & 15) * 4;
    const int row0 = (tid >> 4) * 8;
    const int blockRow = blockIdx.x * BR;
    float acc[8][4];
#pragma unroll
    for (int r = 0; r < 8; ++r)
#pragma unroll
        for (int c = 0; c < 4; ++c) acc[r][c] = 0.f;

    for (int k0 = 0; k0 < K; k0 += BK) {
        int i = tid;
#pragma unroll
        for (int it = 0; it < 4; ++it, i += 256) {
            int row = i >> 3, kq = i & 7;
            int gr = blockRow + row;
            if (gr >= N) gr = N - 1;
            float4 v = *(const float4*)&X[(size_t)gr * K + k0 + kq * 4];
            Xs[(kq * 4 + 0) * S + row] = v.x;
            Xs[(kq * 4 + 1) * S + row] = v.y;
            Xs[(kq * 4 + 2) * S + row] = v.z;
            Xs[(kq * 4 + 3) * S + row] = v.w;
        }
        int j2 = tid;
#pragma unroll
        for (int it = 0; it < 2; ++it, j2 += 256) {
            int k = j2 >> 4, cq = j2 & 15;
            *(float4*)&Ws[k * 64 + cq * 4] =
                *(const float4*)&W[(size_t)(k0 + k) * 64 + cq * 4];
        }
        __syncthreads();
#pragma unroll
        for (int kk = 0; kk < BK; kk += 4) {
            float4 b[4], alo[4], ahi[4];
#pragma unroll
            for (int j = 0; j < 4; ++j) {
                b[j]   = *(const float4*)&Ws[(kk + j) * 64 + c0];
                alo[j] = *(const float4*)&Xs[(kk + j) * S + row0];
                ahi[j] = *(const float4*)&Xs[(kk + j) * S + row0 + 4];
            }
#pragma unroll
            for (int j = 0; j < 4; ++j) {
                const float a_[8] = {alo[j].x, alo[j].y, alo[j].z, alo[j].w,
                                     ahi[j].x, ahi[j].y, ahi[j].z, ahi[j].w};
#pragma unroll
                for (int r = 0; r < 8; ++r) {
                    acc[r][0] += a_[r] * b[j].x;
                    acc[r][1] += a_[r] * b[j].y;
                    acc[r][2] += a_[r] * b[j].z;
                    acc[r][3] += a_[r] * b[j].w;
                }
            }
        }
        __syncthreads();
    }
#pragma unroll
    for (int r = 0; r < 8; ++r) {
        int gr = blockRow + row0 + r;
        if (gr < N) {
            *(float4*)&H[(size_t)gr * 64 + c0] = *(float4*)&acc[r][0];
            ushort4 hb;
            hb.x = f2bf(acc[r][0]); hb.y = f2bf(acc[r][1]);
            hb.z = f2bf(acc[r][2]); hb.w = f2bf(acc[r][3]);
            *(ushort4*)&Hb[(size_t)gr * 64 + c0] = hb;
        }
    }
}

// ---------------- gather-aggregate: wave per node, bf16 messages, fp32 self ---------
__global__ __launch_bounds__(256) void k_gather64(const float* __restrict__ H,
                                                  const unsigned short* __restrict__ Hb,
                                                  const int2* __restrict__ epk,
                                                  const int* __restrict__ rowStart,
                                                  const float* __restrict__ dis,
                                                  const float* __restrict__ b,
                                                  float* __restrict__ out,
                                                  int N, int doRelu) {
    int lane = threadIdx.x & 63;
    int node = (blockIdx.x * 256 + threadIdx.x) >> 6;
    if (node >= N) return;
    int r0 = rowStart[node], r1 = rowStart[node + 1];
    float d = dis[node];
    float acc = H[(size_t)node * 64 + lane] * d * d + b[lane];

    for (int base = r0; base < r1; base += 64) {
        int cnt = min(64, r1 - base);
        int2 pk = (lane < cnt) ? epk[base + lane] : make_int2(0, 0);
        int s = pk.x;
        float nm = __int_as_float(pk.y);
        int j = 0;
        for (; j + 4 <= cnt; j += 4) {
            int s0 = __shfl(s, j, 64),     s1 = __shfl(s, j + 1, 64);
            int s2 = __shfl(s, j + 2, 64), s3 = __shfl(s, j + 3, 64);
            float n0 = __shfl(nm, j, 64),     n1 = __shfl(nm, j + 1, 64);
            float n2 = __shfl(nm, j + 2, 64), n3 = __shfl(nm, j + 3, 64);
            float h0 = bf2f(Hb[(size_t)s0 * 64 + lane]);
            float h1 = bf2f(Hb[(size_t)s1 * 64 + lane]);
            float h2 = bf2f(Hb[(size_t)s2 * 64 + lane]);
            float h3 = bf2f(Hb[(size_t)s3 * 64 + lane]);
            acc += h0 * n0;
            acc += h1 * n1;
            acc += h2 * n2;
            acc += h3 * n3;
        }
        for (; j < cnt; ++j) {
            int sj = __shfl(s, j, 64);
            float nj = __shfl(nm, j, 64);
            acc += bf2f(Hb[(size_t)sj * 64 + lane]) * nj;
        }
    }
    if (doRelu) acc = fmaxf(acc, 0.0f);
    out[(size_t)node * 64 + lane] = acc;
}

// ---------------- layer 3 ----------------
__global__ __launch_bounds__(256) void k_mm1col(const float* __restrict__ H,
                                                const float* __restrict__ W3,
                                                const float* __restrict__ b3,
                                                const float* __restrict__ dis,
                                                float* __restrict__ col,
                                                float* __restrict__ out, int N) {
    int lane = threadIdx.x & 63;
    int node = (blockIdx.x * 256 + threadIdx.x) >> 6;
    if (node >= N) return;
    float v = H[(size_t)node * 64 + lane] * W3[lane];
#pragma unroll
    for (int off = 32; off >= 1; off >>= 1) v += __shfl_down(v, off, 64);
    if (lane == 0) {
        float d = dis[node];
        col[node] = v;
        out[node] = v * d * d + b3[0];
    }
}

__global__ __launch_bounds__(256) void k_gather1(const float* __restrict__ col,
                                                 const int2* __restrict__ epk,
                                                 const int* __restrict__ rowStart,
                                                 float* __restrict__ out, int N) {
    int i = blockIdx.x * 256 + threadIdx.x;
    if (i >= N) return;
    int r0 = rowStart[i], r1 = rowStart[i + 1];
    float acc = 0.0f;
    for (int e = r0; e < r1; ++e) {
        int2 pk = epk[e];
        acc += col[pk.x] * __int_as_float(pk.y);
    }
    out[i] += acc;
}

extern "C" void kernel_launch(void* const* d_in, const int* in_sizes, int n_in,
                              void* d_out, int out_size, void* d_ws, size_t ws_size,
                              hipStream_t stream) {
    const float* x  = (const float*)d_in[0];
    const int*   ei = (const int*)d_in[1];
    const float* W1 = (const float*)d_in[2];
    const float* b1 = (const float*)d_in[3];
    const float* W2 = (const float*)d_in[4];
    const float* b2 = (const float*)d_in[5];
    const float* W3 = (const float*)d_in[6];
    const float* b3 = (const float*)d_in[7];
    float* out = (float*)d_out;

    const int N = in_sizes[0] / IN_DIM;     // 100000
    const int E = in_sizes[1] / 2;          // 1600000
    const int* src = ei;
    const int* dst = ei + E;
    const int NC = (N + 255) >> 8;          // 391 coarse buckets

    // ---- workspace layout ----
    char* w = (char*)d_ws;
    auto alloc = [&](size_t bytes) {
        char* p = w;
        w += (bytes + 1023) & ~(size_t)1023;
        return p;
    };
    float*          dis        = (float*)alloc((size_t)N * 4);
    float*          bufA       = (float*)alloc((size_t)N * 64 * 4);
    float*          bufB       = (float*)alloc((size_t)N * 64 * 4);
    unsigned short* Hb         = (unsigned short*)alloc((size_t)N * 64 * 2);
    float*          col        = (float*)alloc((size_t)N * 4);
    int*            rowStart   = (int*)alloc((size_t)(N + 1) * 4);
    int*            coarseCnt  = (int*)alloc((size_t)MAXC * 4);
    int*            coarseStart= (int*)alloc((size_t)(MAXC + 1) * 4);
    int*            cursorC    = (int*)alloc((size_t)MAXC * 4);
    int2*           epk        = (int2*)alloc((size_t)E * 8);
    int*            tmp1       = (int*)bufA;   // aliased: dead before first k_mmrt

    const int NB_N  = (N + 255) / 256;
    const int NB_MM = (N + 127) / 128;
    const int NB_WV = (N * 64 + 255) / 256;
    const int NB_P  = (E + EPB - 1) / EPB;

    // ---- partition-driven CSR + degrees ----
    hipMemsetAsync(coarseCnt, 0, (size_t)MAXC * sizeof(int), stream);
    k_coarse<<<NB_P, 256, 0, stream>>>(dst, coarseCnt, E, NC);
    k_cscan<<<1, 512, 0, stream>>>(coarseCnt, coarseStart, cursorC, rowStart, NC, N, E);
    k_part1<<<NB_P, 256, 0, stream>>>(src, dst, cursorC, tmp1, E, NC);
    k_deg<<<NC, 256, 0, stream>>>(tmp1, coarseStart, dis, rowStart, N);
    k_place<<<NC, 256, 0, stream>>>(tmp1, coarseStart, rowStart, dis, epk, N);

    // ---- layer 1 ----
    k_mmrt<IN_DIM><<<NB_MM, 256, 0, stream>>>(x, W1, bufA, Hb, N);
    k_gather64<<<NB_WV, 256, 0, stream>>>(bufA, Hb, epk, rowStart, dis, b1, bufB, N, 1);

    // ---- layer 2 ----
    k_mmrt<HID><<<NB_MM, 256, 0, stream>>>(bufB, W2, bufA, Hb, N);
    k_gather64<<<NB_WV, 256, 0, stream>>>(bufA, Hb, epk, rowStart, dis, b2, bufB, N, 1);

    // ---- layer 3 (OUT_DIM = 1) ----
    k_mm1col<<<NB_WV, 256, 0, stream>>>(bufB, W3, b3, dis, col, out, N);
    k_gather1<<<NB_N, 256, 0, stream>>>(col, epk, rowStart, out, N);
}

// Round 8
// 323.204 us; speedup vs baseline: 4.7559x; 1.0382x over previous
//
#include <hip/hip_runtime.h>

#define IN_DIM 128
#define HID 64
#define MAXC 400            // >= ceil(N/256); N=100000 -> 391 coarse buckets
#define EPB 8192

// ---- bf16 helpers (RNE) ----
static __device__ __forceinline__ unsigned short f2bf(float f) {
    unsigned u = __float_as_uint(f);
    u += 0x7FFF + ((u >> 16) & 1);
    return (unsigned short)(u >> 16);
}
static __device__ __forceinline__ float bf2f(unsigned short h) {
    return __uint_as_float((unsigned)h << 16);
}

// ---------------- coarse histogram: LDS-privatized, tiny global merge ----------------
__global__ __launch_bounds__(256) void k_coarse(const int* __restrict__ dst,
                                                int* __restrict__ coarseCnt,
                                                int E, int NC) {
    __shared__ int h[MAXC];
    int tid = threadIdx.x;
    for (int i = tid; i < NC; i += 256) h[i] = 0;
    __syncthreads();
    int e0 = blockIdx.x * EPB, e1 = min(e0 + EPB, E);
    for (int e = e0 + tid; e < e1; e += 256) atomicAdd(&h[dst[e] >> 8], 1);
    __syncthreads();
    for (int i = tid; i < NC; i += 256)
        if (h[i]) atomicAdd(&coarseCnt[i], h[i]);
}

// ---------------- single-block scan over coarse buckets ----------------
__global__ __launch_bounds__(512) void k_cscan(const int* __restrict__ coarseCnt,
                                               int* __restrict__ coarseStart,
                                               int* __restrict__ cursorC,
                                               int* __restrict__ rowStart,
                                               int NC, int N, int E) {
    __shared__ int tmp[512];
    int t = threadIdx.x;
    int v = (t < NC) ? coarseCnt[t] : 0;
    tmp[t] = v;
    __syncthreads();
    for (int off = 1; off < 512; off <<= 1) {
        int a = (t >= off) ? tmp[t - off] : 0;
        __syncthreads();
        tmp[t] += a;
        __syncthreads();
    }
    int excl = tmp[t] - v;
    if (t < NC) { coarseStart[t] = excl; cursorC[t] = excl; }
    if (t == NC - 1) coarseStart[NC] = excl + v;   // == E
    if (t == 0) rowStart[N] = E;
}

// ---------------- pass 1: partition into coarse buckets, 4B payload ----------------
// tmp1[pos] = src | (dloc << 17), dloc = dst & 255
__global__ __launch_bounds__(256) void k_part1(const int* __restrict__ src,
                                               const int* __restrict__ dst,
                                               int* __restrict__ cursorC,
                                               int* __restrict__ tmp1,
                                               int E, int NC) {
    __shared__ int bcnt[MAXC];
    __shared__ int bbase[MAXC];
    int tid = threadIdx.x;
    int e0 = blockIdx.x * EPB;
    int e1 = min(e0 + EPB, E);
    for (int i = tid; i < NC; i += 256) bcnt[i] = 0;
    __syncthreads();
    for (int e = e0 + tid; e < e1; e += 256) atomicAdd(&bcnt[dst[e] >> 8], 1);
    __syncthreads();
    for (int i = tid; i < NC; i += 256) {
        int c = bcnt[i];
        bbase[i] = c ? atomicAdd(&cursorC[i], c) : 0;
    }
    __syncthreads();
    for (int i = tid; i < NC; i += 256) bcnt[i] = 0;
    __syncthreads();
    for (int e = e0 + tid; e < e1; e += 256) {
        int s = src[e], d = dst[e];
        int cb = d >> 8;
        int slot = bbase[cb] + atomicAdd(&bcnt[cb], 1);
        tmp1[slot] = s | ((d & 255) << 17);
    }
}

// ---------------- pass 2 (fused): per-bucket degree->dis/rowStart, then place ----------
__global__ __launch_bounds__(256) void k_degplace(const int* __restrict__ tmp1,
                                                  const int* __restrict__ coarseStart,
                                                  float* __restrict__ dis,
                                                  int* __restrict__ rowStart,
                                                  int* __restrict__ esrc, int N) {
    __shared__ int hist[256];
    __shared__ int scn[256];
    __shared__ int cur[256];
    int tid = threadIdx.x;
    int cb = blockIdx.x;
    int node0 = cb << 8;
    hist[tid] = 0;
    __syncthreads();
    int r0 = coarseStart[cb], r1 = coarseStart[cb + 1];
    for (int e = r0 + tid; e < r1; e += 256)
        atomicAdd(&hist[((unsigned)tmp1[e]) >> 17], 1);
    __syncthreads();
    int v = hist[tid];
    scn[tid] = v;
    __syncthreads();
    for (int off = 1; off < 256; off <<= 1) {
        int a = (tid >= off) ? scn[tid - off] : 0;
        __syncthreads();
        scn[tid] += a;
        __syncthreads();
    }
    int myStart = r0 + scn[tid] - v;      // exclusive within bucket + base
    cur[tid] = myStart;
    int node = node0 + tid;
    if (node < N) {
        dis[node] = rsqrtf((float)v + 1.0f);
        rowStart[node] = myStart;
    }
    __syncthreads();
    // place: writes land in a ~26KB L2-resident window
    for (int e = r0 + tid; e < r1; e += 256) {
        int pk = tmp1[e];
        int dl = ((unsigned)pk) >> 17;
        int pos = atomicAdd(&cur[dl], 1);
        esrc[pos] = pk & 0x1FFFF;
    }
}

// ------- register-tiled transform: Hbs[N,64] = bf16( (X @ W) * dis[row] ) -------
template <int K>
__global__ __launch_bounds__(256) void k_mmrt(const float* __restrict__ X,
                                              const float* __restrict__ W,
                                              const float* __restrict__ dis,
                                              unsigned short* __restrict__ Hbs, int N) {
    constexpr int BR = 128, BK = 32, S = 132;
    __shared__ float Xs[BK * S];
    __shared__ float Ws[BK * 64];
    const int tid = threadIdx.x;
    const int c0 = (tid & 15) * 4;
    const int row0 = (tid >> 4) * 8;
    const int blockRow = blockIdx.x * BR;
    float acc[8][4];
#pragma unroll
    for (int r = 0; r < 8; ++r)
#pragma unroll
        for (int c = 0; c < 4; ++c) acc[r][c] = 0.f;

    for (int k0 = 0; k0 < K; k0 += BK) {
        int i = tid;
#pragma unroll
        for (int it = 0; it < 4; ++it, i += 256) {
            int row = i >> 3, kq = i & 7;
            int gr = blockRow + row;
            if (gr >= N) gr = N - 1;
            float4 v = *(const float4*)&X[(size_t)gr * K + k0 + kq * 4];
            Xs[(kq * 4 + 0) * S + row] = v.x;
            Xs[(kq * 4 + 1) * S + row] = v.y;
            Xs[(kq * 4 + 2) * S + row] = v.z;
            Xs[(kq * 4 + 3) * S + row] = v.w;
        }
        int j2 = tid;
#pragma unroll
        for (int it = 0; it < 2; ++it, j2 += 256) {
            int k = j2 >> 4, cq = j2 & 15;
            *(float4*)&Ws[k * 64 + cq * 4] =
                *(const float4*)&W[(size_t)(k0 + k) * 64 + cq * 4];
        }
        __syncthreads();
#pragma unroll
        for (int kk = 0; kk < BK; kk += 4) {
            float4 b[4], alo[4], ahi[4];
#pragma unroll
            for (int j = 0; j < 4; ++j) {
                b[j]   = *(const float4*)&Ws[(kk + j) * 64 + c0];
                alo[j] = *(const float4*)&Xs[(kk + j) * S + row0];
                ahi[j] = *(const float4*)&Xs[(kk + j) * S + row0 + 4];
            }
#pragma unroll
            for (int j = 0; j < 4; ++j) {
                const float a_[8] = {alo[j].x, alo[j].y, alo[j].z, alo[j].w,
                                     ahi[j].x, ahi[j].y, ahi[j].z, ahi[j].w};
#pragma unroll
                for (int r = 0; r < 8; ++r) {
                    acc[r][0] += a_[r] * b[j].x;
                    acc[r][1] += a_[r] * b[j].y;
                    acc[r][2] += a_[r] * b[j].z;
                    acc[r][3] += a_[r] * b[j].w;
                }
            }
        }
        __syncthreads();
    }
#pragma unroll
    for (int r = 0; r < 8; ++r) {
        int gr = blockRow + row0 + r;
        if (gr < N) {
            float dsc = dis[gr];
            ushort4 hb;
            hb.x = f2bf(acc[r][0] * dsc); hb.y = f2bf(acc[r][1] * dsc);
            hb.z = f2bf(acc[r][2] * dsc); hb.w = f2bf(acc[r][3] * dsc);
            *(ushort4*)&Hbs[(size_t)gr * 64 + c0] = hb;
        }
    }
}

// ------- gather-aggregate: wave per node, add-only bf16 messages -------
// out[i,:] = relu( (sum_{s} Hbs[s,:] + Hbs[i,:]) * dis[i] + b )
__global__ __launch_bounds__(256) void k_gather64(const unsigned short* __restrict__ Hbs,
                                                  const int* __restrict__ esrc,
                                                  const int* __restrict__ rowStart,
                                                  const float* __restrict__ dis,
                                                  const float* __restrict__ b,
                                                  float* __restrict__ out,
                                                  int N, int doRelu) {
    int lane = threadIdx.x & 63;
    int node = (blockIdx.x * 256 + threadIdx.x) >> 6;
    if (node >= N) return;
    int r0 = rowStart[node], r1 = rowStart[node + 1];
    float dn = dis[node];
    float acc = bf2f(Hbs[(size_t)node * 64 + lane]);   // self: h_i * dis_i

    for (int base = r0; base < r1; base += 64) {
        int cnt = min(64, r1 - base);
        int s = (lane < cnt) ? esrc[base + lane] : 0;
        int j = 0;
        for (; j + 4 <= cnt; j += 4) {
            int s0 = __shfl(s, j, 64),     s1 = __shfl(s, j + 1, 64);
            int s2 = __shfl(s, j + 2, 64), s3 = __shfl(s, j + 3, 64);
            float h0 = bf2f(Hbs[(size_t)s0 * 64 + lane]);
            float h1 = bf2f(Hbs[(size_t)s1 * 64 + lane]);
            float h2 = bf2f(Hbs[(size_t)s2 * 64 + lane]);
            float h3 = bf2f(Hbs[(size_t)s3 * 64 + lane]);
            acc += (h0 + h1) + (h2 + h3);
        }
        for (; j < cnt; ++j) {
            int sj = __shfl(s, j, 64);
            acc += bf2f(Hbs[(size_t)sj * 64 + lane]);
        }
    }
    float val = acc * dn + b[lane];
    if (doRelu) val = fmaxf(val, 0.0f);
    out[(size_t)node * 64 + lane] = val;
}

// ---------------- layer 3: col = H.W3 ; colS = col*dis ; out = col*dis^2 + b3 --------
__global__ __launch_bounds__(256) void k_mm1col(const float* __restrict__ H,
                                                const float* __restrict__ W3,
                                                const float* __restrict__ b3,
                                                const float* __restrict__ dis,
                                                float* __restrict__ colS,
                                                float* __restrict__ out, int N) {
    int lane = threadIdx.x & 63;
    int node = (blockIdx.x * 256 + threadIdx.x) >> 6;
    if (node >= N) return;
    float v = H[(size_t)node * 64 + lane] * W3[lane];
#pragma unroll
    for (int off = 32; off >= 1; off >>= 1) v += __shfl_down(v, off, 64);
    if (lane == 0) {
        float d = dis[node];
        colS[node] = v * d;
        out[node] = v * d * d + b3[0];
    }
}

// out[i] += dis[i] * sum colS[src]
__global__ __launch_bounds__(256) void k_gather1(const float* __restrict__ colS,
                                                 const int* __restrict__ esrc,
                                                 const int* __restrict__ rowStart,
                                                 const float* __restrict__ dis,
                                                 float* __restrict__ out, int N) {
    int i = blockIdx.x * 256 + threadIdx.x;
    if (i >= N) return;
    int r0 = rowStart[i], r1 = rowStart[i + 1];
    float acc = 0.0f;
    for (int e = r0; e < r1; ++e) acc += colS[esrc[e]];
    out[i] += acc * dis[i];
}

extern "C" void kernel_launch(void* const* d_in, const int* in_sizes, int n_in,
                              void* d_out, int out_size, void* d_ws, size_t ws_size,
                              hipStream_t stream) {
    const float* x  = (const float*)d_in[0];
    const int*   ei = (const int*)d_in[1];
    const float* W1 = (const float*)d_in[2];
    const float* b1 = (const float*)d_in[3];
    const float* W2 = (const float*)d_in[4];
    const float* b2 = (const float*)d_in[5];
    const float* W3 = (const float*)d_in[6];
    const float* b3 = (const float*)d_in[7];
    float* out = (float*)d_out;

    const int N = in_sizes[0] / IN_DIM;     // 100000
    const int E = in_sizes[1] / 2;          // 1600000
    const int* src = ei;
    const int* dst = ei + E;
    const int NC = (N + 255) >> 8;          // 391 coarse buckets

    // ---- workspace layout ----
    char* w = (char*)d_ws;
    auto alloc = [&](size_t bytes) {
        char* p = w;
        w += (bytes + 1023) & ~(size_t)1023;
        return p;
    };
    float*          dis        = (float*)alloc((size_t)N * 4);
    float*          bufB       = (float*)alloc((size_t)N * 64 * 4);   // layer-1 out
    float*          bufC       = (float*)alloc((size_t)N * 64 * 4);   // layer-2 out
    unsigned short* Hbs        = (unsigned short*)alloc((size_t)N * 64 * 2);
    float*          colS       = (float*)alloc((size_t)N * 4);
    int*            rowStart   = (int*)alloc((size_t)(N + 1) * 4);
    int*            coarseCnt  = (int*)alloc((size_t)MAXC * 4);
    int*            coarseStart= (int*)alloc((size_t)(MAXC + 1) * 4);
    int*            cursorC    = (int*)alloc((size_t)MAXC * 4);
    int*            esrc       = (int*)alloc((size_t)E * 4);
    int*            tmp1       = (int*)alloc((size_t)E * 4);

    const int NB_N  = (N + 255) / 256;
    const int NB_MM = (N + 127) / 128;
    const int NB_WV = (N * 64 + 255) / 256;
    const int NB_P  = (E + EPB - 1) / EPB;

    // ---- partition-driven CSR + degrees ----
    hipMemsetAsync(coarseCnt, 0, (size_t)MAXC * sizeof(int), stream);
    k_coarse<<<NB_P, 256, 0, stream>>>(dst, coarseCnt, E, NC);
    k_cscan<<<1, 512, 0, stream>>>(coarseCnt, coarseStart, cursorC, rowStart, NC, N, E);
    k_part1<<<NB_P, 256, 0, stream>>>(src, dst, cursorC, tmp1, E, NC);
    k_degplace<<<NC, 256, 0, stream>>>(tmp1, coarseStart, dis, rowStart, esrc, N);

    // ---- layer 1 ----
    k_mmrt<IN_DIM><<<NB_MM, 256, 0, stream>>>(x, W1, dis, Hbs, N);
    k_gather64<<<NB_WV, 256, 0, stream>>>(Hbs, esrc, rowStart, dis, b1, bufB, N, 1);

    // ---- layer 2 ----
    k_mmrt<HID><<<NB_MM, 256, 0, stream>>>(bufB, W2, dis, Hbs, N);
    k_gather64<<<NB_WV, 256, 0, stream>>>(Hbs, esrc, rowStart, dis, b2, bufC, N, 1);

    // ---- layer 3 (OUT_DIM = 1) ----
    k_mm1col<<<NB_WV, 256, 0, stream>>>(bufC, W3, b3, dis, colS, out, N);
    k_gather1<<<NB_N, 256, 0, stream>>>(colS, esrc, rowStart, dis, out, N);
}

// Round 9
// 306.738 us; speedup vs baseline: 5.0112x; 1.0537x over previous
//
#include <hip/hip_runtime.h>

#define IN_DIM 128
#define HID 64
#define MAXC 400            // >= ceil(N/256); N=100000 -> 391 coarse buckets
#define EPB 8192
#define CAP 6144            // padded bucket capacity (mean 4096, 5-sigma ~4420)

// ---- bf16 helpers (RNE) ----
static __device__ __forceinline__ unsigned short f2bf(float f) {
    unsigned u = __float_as_uint(f);
    u += 0x7FFF + ((u >> 16) & 1);
    return (unsigned short)(u >> 16);
}
static __device__ __forceinline__ float bf2f(unsigned short h) {
    return __uint_as_float((unsigned)h << 16);
}

// ---- pass 1: partition into padded coarse-bucket regions (no pre-scan needed) ----
// tmp1[cb*CAP + slot] = src | (dloc << 17), dloc = dst & 255 ; cursorC[cb] = count
__global__ __launch_bounds__(256) void k_part1(const int* __restrict__ src,
                                               const int* __restrict__ dst,
                                               int* __restrict__ cursorC,
                                               int* __restrict__ tmp1,
                                               int E, int NC) {
    __shared__ int bcnt[MAXC];
    __shared__ int bbase[MAXC];
    int tid = threadIdx.x;
    int e0 = blockIdx.x * EPB;
    int e1 = min(e0 + EPB, E);
    for (int i = tid; i < NC; i += 256) bcnt[i] = 0;
    __syncthreads();
    for (int e = e0 + tid; e < e1; e += 256) atomicAdd(&bcnt[dst[e] >> 8], 1);
    __syncthreads();
    for (int i = tid; i < NC; i += 256) {
        int c = bcnt[i];
        bbase[i] = c ? atomicAdd(&cursorC[i], c) : 0;
    }
    __syncthreads();
    for (int i = tid; i < NC; i += 256) bcnt[i] = 0;
    __syncthreads();
    for (int e = e0 + tid; e < e1; e += 256) {
        int s = src[e], d = dst[e];
        int cb = d >> 8;
        int slot = bbase[cb] + atomicAdd(&bcnt[cb], 1);
        tmp1[(size_t)cb * CAP + slot] = s | ((d & 255) << 17);
    }
}

// ---- single-block scan over bucket counts -> global CSR bases ----
__global__ __launch_bounds__(512) void k_cscan(const int* __restrict__ cursorC,
                                               int* __restrict__ coarseStart,
                                               int* __restrict__ rowStart,
                                               int NC, int N, int E) {
    __shared__ int tmp[512];
    int t = threadIdx.x;
    int v = (t < NC) ? cursorC[t] : 0;
    tmp[t] = v;
    __syncthreads();
    for (int off = 1; off < 512; off <<= 1) {
        int a = (t >= off) ? tmp[t - off] : 0;
        __syncthreads();
        tmp[t] += a;
        __syncthreads();
    }
    int excl = tmp[t] - v;
    if (t < NC) coarseStart[t] = excl;
    if (t == NC - 1) coarseStart[NC] = excl + v;   // == E
    if (t == 0) rowStart[N] = E;
}

// ---- pass 2 (fused): per-bucket degree->dis/rowStart, then place into CSR ----
__global__ __launch_bounds__(256) void k_degplace(const int* __restrict__ tmp1,
                                                  const int* __restrict__ cursorC,
                                                  const int* __restrict__ coarseStart,
                                                  float* __restrict__ dis,
                                                  int* __restrict__ rowStart,
                                                  int* __restrict__ esrc, int N) {
    __shared__ int hist[256];
    __shared__ int scn[256];
    __shared__ int cur[256];
    int tid = threadIdx.x;
    int cb = blockIdx.x;
    int node0 = cb << 8;
    const int cnt = cursorC[cb];
    const size_t bp = (size_t)cb * CAP;
    const int g0 = coarseStart[cb];
    hist[tid] = 0;
    __syncthreads();
    for (int i = tid; i < cnt; i += 256)
        atomicAdd(&hist[((unsigned)tmp1[bp + i]) >> 17], 1);
    __syncthreads();
    int v = hist[tid];
    scn[tid] = v;
    __syncthreads();
    for (int off = 1; off < 256; off <<= 1) {
        int a = (tid >= off) ? scn[tid - off] : 0;
        __syncthreads();
        scn[tid] += a;
        __syncthreads();
    }
    int myStart = g0 + scn[tid] - v;
    cur[tid] = myStart;
    int node = node0 + tid;
    if (node < N) {
        dis[node] = rsqrtf((float)v + 1.0f);
        rowStart[node] = myStart;
    }
    __syncthreads();
    for (int i = tid; i < cnt; i += 256) {
        int pk = tmp1[bp + i];
        int dl = ((unsigned)pk) >> 17;
        int pos = atomicAdd(&cur[dl], 1);
        esrc[pos] = pk & 0x1FFFF;
    }
}

// ------- register-tiled transform: Hbs[N,64] = bf16( (X @ W) * dis[row] ) -------
template <int K>
__global__ __launch_bounds__(256) void k_mmrt(const float* __restrict__ X,
                                              const float* __restrict__ W,
                                              const float* __restrict__ dis,
                                              unsigned short* __restrict__ Hbs, int N) {
    constexpr int BR = 128, BK = 32, S = 132;
    __shared__ float Xs[BK * S];
    __shared__ float Ws[BK * 64];
    const int tid = threadIdx.x;
    const int c0 = (tid & 15) * 4;
    const int row0 = (tid >> 4) * 8;
    const int blockRow = blockIdx.x * BR;
    float acc[8][4];
#pragma unroll
    for (int r = 0; r < 8; ++r)
#pragma unroll
        for (int c = 0; c < 4; ++c) acc[r][c] = 0.f;

    for (int k0 = 0; k0 < K; k0 += BK) {
        int i = tid;
#pragma unroll
        for (int it = 0; it < 4; ++it, i += 256) {
            int row = i >> 3, kq = i & 7;
            int gr = blockRow + row;
            if (gr >= N) gr = N - 1;
            float4 v = *(const float4*)&X[(size_t)gr * K + k0 + kq * 4];
            Xs[(kq * 4 + 0) * S + row] = v.x;
            Xs[(kq * 4 + 1) * S + row] = v.y;
            Xs[(kq * 4 + 2) * S + row] = v.z;
            Xs[(kq * 4 + 3) * S + row] = v.w;
        }
        int j2 = tid;
#pragma unroll
        for (int it = 0; it < 2; ++it, j2 += 256) {
            int k = j2 >> 4, cq = j2 & 15;
            *(float4*)&Ws[k * 64 + cq * 4] =
                *(const float4*)&W[(size_t)(k0 + k) * 64 + cq * 4];
        }
        __syncthreads();
#pragma unroll
        for (int kk = 0; kk < BK; kk += 4) {
            float4 b[4], alo[4], ahi[4];
#pragma unroll
            for (int j = 0; j < 4; ++j) {
                b[j]   = *(const float4*)&Ws[(kk + j) * 64 + c0];
                alo[j] = *(const float4*)&Xs[(kk + j) * S + row0];
                ahi[j] = *(const float4*)&Xs[(kk + j) * S + row0 + 4];
            }
#pragma unroll
            for (int j = 0; j < 4; ++j) {
                const float a_[8] = {alo[j].x, alo[j].y, alo[j].z, alo[j].w,
                                     ahi[j].x, ahi[j].y, ahi[j].z, ahi[j].w};
#pragma unroll
                for (int r = 0; r < 8; ++r) {
                    acc[r][0] += a_[r] * b[j].x;
                    acc[r][1] += a_[r] * b[j].y;
                    acc[r][2] += a_[r] * b[j].z;
                    acc[r][3] += a_[r] * b[j].w;
                }
            }
        }
        __syncthreads();
    }
#pragma unroll
    for (int r = 0; r < 8; ++r) {
        int gr = blockRow + row0 + r;
        if (gr < N) {
            float dsc = dis[gr];
            ushort4 hb;
            hb.x = f2bf(acc[r][0] * dsc); hb.y = f2bf(acc[r][1] * dsc);
            hb.z = f2bf(acc[r][2] * dsc); hb.w = f2bf(acc[r][3] * dsc);
            *(ushort4*)&Hbs[(size_t)gr * 64 + c0] = hb;
        }
    }
}

// ------- gather-aggregate: wave per 4 nodes (amortized latency chain) -------
// out[i,:] = relu( (sum_{s} Hbs[s,:] + Hbs[i,:]) * dis[i] + b )
#define GNODE(AK, RA, RB)                                                     \
    {                                                                         \
        int j0 = RA - base; j0 = max(j0, 0);                                  \
        int j1 = RB - base; j1 = min(j1, cnt);                                \
        int j = j0;                                                           \
        for (; j + 4 <= j1; j += 4) {                                         \
            int s0 = __shfl(e, j, 64),     s1 = __shfl(e, j + 1, 64);         \
            int s2 = __shfl(e, j + 2, 64), s3 = __shfl(e, j + 3, 64);         \
            float h0 = bf2f(Hbs[(size_t)s0 * 64 + lane]);                     \
            float h1 = bf2f(Hbs[(size_t)s1 * 64 + lane]);                     \
            float h2 = bf2f(Hbs[(size_t)s2 * 64 + lane]);                     \
            float h3 = bf2f(Hbs[(size_t)s3 * 64 + lane]);                     \
            AK += (h0 + h1) + (h2 + h3);                                      \
        }                                                                     \
        for (; j < j1; ++j) {                                                 \
            int sj = __shfl(e, j, 64);                                        \
            AK += bf2f(Hbs[(size_t)sj * 64 + lane]);                          \
        }                                                                     \
    }

__global__ __launch_bounds__(256) void k_gather64(const unsigned short* __restrict__ Hbs,
                                                  const int* __restrict__ esrc,
                                                  const int* __restrict__ rowStart,
                                                  const float* __restrict__ dis,
                                                  const float* __restrict__ b,
                                                  float* __restrict__ out,
                                                  int N, int doRelu) {
    int lane = threadIdx.x & 63;
    int wave = (blockIdx.x * 256 + threadIdx.x) >> 6;
    int g0 = wave * 4;
    if (g0 >= N) return;

    // bounds: rowStart[g0 .. g0+4] via one coalesced load + shuffles
    int rb = rowStart[min(g0 + lane, N)];
    int R0 = __shfl(rb, 0, 64), R1 = __shfl(rb, 1, 64);
    int R2 = __shfl(rb, 2, 64), R3 = __shfl(rb, 3, 64);
    int R4 = __shfl(rb, 4, 64);
    float dv = dis[min(g0 + lane, N - 1)];
    float d0 = __shfl(dv, 0, 64), d1 = __shfl(dv, 1, 64);
    float d2 = __shfl(dv, 2, 64), d3 = __shfl(dv, 3, 64);
    float bl = b[lane];

    // accumulators seeded with self terms (h_i * dis_i)
    float a0 = bf2f(Hbs[(size_t)g0 * 64 + lane]);
    float a1 = bf2f(Hbs[(size_t)min(g0 + 1, N - 1) * 64 + lane]);
    float a2 = bf2f(Hbs[(size_t)min(g0 + 2, N - 1) * 64 + lane]);
    float a3 = bf2f(Hbs[(size_t)min(g0 + 3, N - 1) * 64 + lane]);

    for (int base = R0; base < R4; base += 64) {
        int cnt = min(64, R4 - base);
        int e = (lane < cnt) ? esrc[base + lane] : 0;
        GNODE(a0, R0, R1)
        GNODE(a1, R1, R2)
        GNODE(a2, R2, R3)
        GNODE(a3, R3, R4)
    }

    float v0 = a0 * d0 + bl, v1 = a1 * d1 + bl;
    float v2 = a2 * d2 + bl, v3 = a3 * d3 + bl;
    if (doRelu) {
        v0 = fmaxf(v0, 0.f); v1 = fmaxf(v1, 0.f);
        v2 = fmaxf(v2, 0.f); v3 = fmaxf(v3, 0.f);
    }
    out[(size_t)g0 * 64 + lane] = v0;
    if (g0 + 1 < N) out[(size_t)(g0 + 1) * 64 + lane] = v1;
    if (g0 + 2 < N) out[(size_t)(g0 + 2) * 64 + lane] = v2;
    if (g0 + 3 < N) out[(size_t)(g0 + 3) * 64 + lane] = v3;
}

// ---------------- layer 3: col = H.W3 ; colS = col*dis ; out = col*dis^2 + b3 --------
__global__ __launch_bounds__(256) void k_mm1col(const float* __restrict__ H,
                                                const float* __restrict__ W3,
                                                const float* __restrict__ b3,
                                                const float* __restrict__ dis,
                                                float* __restrict__ colS,
                                                float* __restrict__ out, int N) {
    int lane = threadIdx.x & 63;
    int node = (blockIdx.x * 256 + threadIdx.x) >> 6;
    if (node >= N) return;
    float v = H[(size_t)node * 64 + lane] * W3[lane];
#pragma unroll
    for (int off = 32; off >= 1; off >>= 1) v += __shfl_down(v, off, 64);
    if (lane == 0) {
        float d = dis[node];
        colS[node] = v * d;
        out[node] = v * d * d + b3[0];
    }
}

// out[i] += dis[i] * sum colS[src]
__global__ __launch_bounds__(256) void k_gather1(const float* __restrict__ colS,
                                                 const int* __restrict__ esrc,
                                                 const int* __restrict__ rowStart,
                                                 const float* __restrict__ dis,
                                                 float* __restrict__ out, int N) {
    int i = blockIdx.x * 256 + threadIdx.x;
    if (i >= N) return;
    int r0 = rowStart[i], r1 = rowStart[i + 1];
    float acc = 0.0f;
    for (int e = r0; e < r1; ++e) acc += colS[esrc[e]];
    out[i] += acc * dis[i];
}

extern "C" void kernel_launch(void* const* d_in, const int* in_sizes, int n_in,
                              void* d_out, int out_size, void* d_ws, size_t ws_size,
                              hipStream_t stream) {
    const float* x  = (const float*)d_in[0];
    const int*   ei = (const int*)d_in[1];
    const float* W1 = (const float*)d_in[2];
    const float* b1 = (const float*)d_in[3];
    const float* W2 = (const float*)d_in[4];
    const float* b2 = (const float*)d_in[5];
    const float* W3 = (const float*)d_in[6];
    const float* b3 = (const float*)d_in[7];
    float* out = (float*)d_out;

    const int N = in_sizes[0] / IN_DIM;     // 100000
    const int E = in_sizes[1] / 2;          // 1600000
    const int* src = ei;
    const int* dst = ei + E;
    const int NC = (N + 255) >> 8;          // 391 coarse buckets

    // ---- workspace layout ----
    char* w = (char*)d_ws;
    auto alloc = [&](size_t bytes) {
        char* p = w;
        w += (bytes + 1023) & ~(size_t)1023;
        return p;
    };
    float*          dis        = (float*)alloc((size_t)N * 4);
    float*          bufB       = (float*)alloc((size_t)N * 64 * 4);   // layer-1 out
    float*          bufC       = (float*)alloc((size_t)N * 64 * 4);   // layer-2 out
    unsigned short* Hbs        = (unsigned short*)alloc((size_t)N * 64 * 2);
    float*          colS       = (float*)alloc((size_t)N * 4);
    int*            rowStart   = (int*)alloc((size_t)(N + 1) * 4);
    int*            cursorC    = (int*)alloc((size_t)MAXC * 4);
    int*            coarseStart= (int*)alloc((size_t)(MAXC + 1) * 4);
    int*            esrc       = (int*)alloc((size_t)E * 4);
    int*            tmp1       = (int*)alloc((size_t)MAXC * CAP * 4);

    const int NB_N  = (N + 255) / 256;
    const int NB_MM = (N + 127) / 128;
    const int NB_WV = (N * 64 + 255) / 256;
    const int NB_G4 = ((N + 3) / 4 * 64 + 255) / 256;   // 4 nodes per wave
    const int NB_P  = (E + EPB - 1) / EPB;

    // ---- partition-driven CSR + degrees (no pre-histogram pass) ----
    hipMemsetAsync(cursorC, 0, (size_t)MAXC * sizeof(int), stream);
    k_part1<<<NB_P, 256, 0, stream>>>(src, dst, cursorC, tmp1, E, NC);
    k_cscan<<<1, 512, 0, stream>>>(cursorC, coarseStart, rowStart, NC, N, E);
    k_degplace<<<NC, 256, 0, stream>>>(tmp1, cursorC, coarseStart, dis, rowStart, esrc, N);

    // ---- layer 1 ----
    k_mmrt<IN_DIM><<<NB_MM, 256, 0, stream>>>(x, W1, dis, Hbs, N);
    k_gather64<<<NB_G4, 256, 0, stream>>>(Hbs, esrc, rowStart, dis, b1, bufB, N, 1);

    // ---- layer 2 ----
    k_mmrt<HID><<<NB_MM, 256, 0, stream>>>(bufB, W2, dis, Hbs, N);
    k_gather64<<<NB_G4, 256, 0, stream>>>(Hbs, esrc, rowStart, dis, b2, bufC, N, 1);

    // ---- layer 3 (OUT_DIM = 1) ----
    k_mm1col<<<NB_WV, 256, 0, stream>>>(bufC, W3, b3, dis, colS, out, N);
    k_gather1<<<NB_N, 256, 0, stream>>>(colS, esrc, rowStart, dis, out, N);
}

// Round 10
// 298.981 us; speedup vs baseline: 5.1412x; 1.0259x over previous
//
#include <hip/hip_runtime.h>

#define IN_DIM 128
#define HID 64
#define MAXC 400            // >= ceil(N/256); N=100000 -> 391 coarse buckets
#define EPB 8192
#define CAP 6144            // padded bucket capacity (mean 4096, 5-sigma ~4420)

// ---- bf16 helpers (RNE) ----
static __device__ __forceinline__ unsigned short f2bf(float f) {
    unsigned u = __float_as_uint(f);
    u += 0x7FFF + ((u >> 16) & 1);
    return (unsigned short)(u >> 16);
}
static __device__ __forceinline__ float bf2f(unsigned short h) {
    return __uint_as_float((unsigned)h << 16);
}

// ---- pass 1: partition into padded coarse-bucket regions (no pre-scan needed) ----
// tmp1[cb*CAP + slot] = src | (dloc << 17), dloc = dst & 255 ; cursorC[cb] = count
__global__ __launch_bounds__(256) void k_part1(const int* __restrict__ src,
                                               const int* __restrict__ dst,
                                               int* __restrict__ cursorC,
                                               int* __restrict__ tmp1,
                                               int E, int NC) {
    __shared__ int bcnt[MAXC];
    __shared__ int bbase[MAXC];
    int tid = threadIdx.x;
    int e0 = blockIdx.x * EPB;
    int e1 = min(e0 + EPB, E);
    for (int i = tid; i < NC; i += 256) bcnt[i] = 0;
    __syncthreads();
    for (int e = e0 + tid; e < e1; e += 256) atomicAdd(&bcnt[dst[e] >> 8], 1);
    __syncthreads();
    for (int i = tid; i < NC; i += 256) {
        int c = bcnt[i];
        bbase[i] = c ? atomicAdd(&cursorC[i], c) : 0;
    }
    __syncthreads();
    for (int i = tid; i < NC; i += 256) bcnt[i] = 0;
    __syncthreads();
    for (int e = e0 + tid; e < e1; e += 256) {
        int s = src[e], d = dst[e];
        int cb = d >> 8;
        int slot = bbase[cb] + atomicAdd(&bcnt[cb], 1);
        tmp1[(size_t)cb * CAP + slot] = s | ((d & 255) << 17);
    }
}

// ---- single-block scan over bucket counts -> global CSR bases ----
__global__ __launch_bounds__(512) void k_cscan(const int* __restrict__ cursorC,
                                               int* __restrict__ coarseStart,
                                               int* __restrict__ rowStart,
                                               int NC, int N, int E) {
    __shared__ int tmp[512];
    int t = threadIdx.x;
    int v = (t < NC) ? cursorC[t] : 0;
    tmp[t] = v;
    __syncthreads();
    for (int off = 1; off < 512; off <<= 1) {
        int a = (t >= off) ? tmp[t - off] : 0;
        __syncthreads();
        tmp[t] += a;
        __syncthreads();
    }
    int excl = tmp[t] - v;
    if (t < NC) coarseStart[t] = excl;
    if (t == NC - 1) coarseStart[NC] = excl + v;   // == E
    if (t == 0) rowStart[N] = E;
}

// ---- pass 2 (fused): per-bucket degree->dis/rowStart, then place into CSR ----
// esrc holds BYTE offsets (s*128) for the gather's dword addressing.
__global__ __launch_bounds__(256) void k_degplace(const int* __restrict__ tmp1,
                                                  const int* __restrict__ cursorC,
                                                  const int* __restrict__ coarseStart,
                                                  float* __restrict__ dis,
                                                  int* __restrict__ rowStart,
                                                  int* __restrict__ esrc, int N) {
    __shared__ int hist[256];
    __shared__ int scn[256];
    __shared__ int cur[256];
    int tid = threadIdx.x;
    int cb = blockIdx.x;
    int node0 = cb << 8;
    const int cnt = cursorC[cb];
    const size_t bp = (size_t)cb * CAP;
    const int g0 = coarseStart[cb];
    hist[tid] = 0;
    __syncthreads();
    for (int i = tid; i < cnt; i += 256)
        atomicAdd(&hist[((unsigned)tmp1[bp + i]) >> 17], 1);
    __syncthreads();
    int v = hist[tid];
    scn[tid] = v;
    __syncthreads();
    for (int off = 1; off < 256; off <<= 1) {
        int a = (tid >= off) ? scn[tid - off] : 0;
        __syncthreads();
        scn[tid] += a;
        __syncthreads();
    }
    int myStart = g0 + scn[tid] - v;
    cur[tid] = myStart;
    int node = node0 + tid;
    if (node < N) {
        dis[node] = rsqrtf((float)v + 1.0f);
        rowStart[node] = myStart;
    }
    __syncthreads();
    for (int i = tid; i < cnt; i += 256) {
        int pk = tmp1[bp + i];
        int dl = ((unsigned)pk) >> 17;
        int pos = atomicAdd(&cur[dl], 1);
        esrc[pos] = (pk & 0x1FFFF) << 7;     // byte offset of bf16 row
    }
}

// ------- register-tiled transform: Hbs[N,64] = bf16( (X @ W) * dis[row] ) -------
template <int K>
__global__ __launch_bounds__(256) void k_mmrt(const float* __restrict__ X,
                                              const float* __restrict__ W,
                                              const float* __restrict__ dis,
                                              unsigned short* __restrict__ Hbs, int N) {
    constexpr int BR = 128, BK = 32, S = 132;
    __shared__ float Xs[BK * S];
    __shared__ float Ws[BK * 64];
    const int tid = threadIdx.x;
    const int c0 = (tid & 15) * 4;
    const int row0 = (tid >> 4) * 8;
    const int blockRow = blockIdx.x * BR;
    float acc[8][4];
#pragma unroll
    for (int r = 0; r < 8; ++r)
#pragma unroll
        for (int c = 0; c < 4; ++c) acc[r][c] = 0.f;

    for (int k0 = 0; k0 < K; k0 += BK) {
        int i = tid;
#pragma unroll
        for (int it = 0; it < 4; ++it, i += 256) {
            int row = i >> 3, kq = i & 7;
            int gr = blockRow + row;
            if (gr >= N) gr = N - 1;
            float4 v = *(const float4*)&X[(size_t)gr * K + k0 + kq * 4];
            Xs[(kq * 4 + 0) * S + row] = v.x;
            Xs[(kq * 4 + 1) * S + row] = v.y;
            Xs[(kq * 4 + 2) * S + row] = v.z;
            Xs[(kq * 4 + 3) * S + row] = v.w;
        }
        int j2 = tid;
#pragma unroll
        for (int it = 0; it < 2; ++it, j2 += 256) {
            int k = j2 >> 4, cq = j2 & 15;
            *(float4*)&Ws[k * 64 + cq * 4] =
                *(const float4*)&W[(size_t)(k0 + k) * 64 + cq * 4];
        }
        __syncthreads();
#pragma unroll
        for (int kk = 0; kk < BK; kk += 4) {
            float4 b[4], alo[4], ahi[4];
#pragma unroll
            for (int j = 0; j < 4; ++j) {
                b[j]   = *(const float4*)&Ws[(kk + j) * 64 + c0];
                alo[j] = *(const float4*)&Xs[(kk + j) * S + row0];
                ahi[j] = *(const float4*)&Xs[(kk + j) * S + row0 + 4];
            }
#pragma unroll
            for (int j = 0; j < 4; ++j) {
                const float a_[8] = {alo[j].x, alo[j].y, alo[j].z, alo[j].w,
                                     ahi[j].x, ahi[j].y, ahi[j].z, ahi[j].w};
#pragma unroll
                for (int r = 0; r < 8; ++r) {
                    acc[r][0] += a_[r] * b[j].x;
                    acc[r][1] += a_[r] * b[j].y;
                    acc[r][2] += a_[r] * b[j].z;
                    acc[r][3] += a_[r] * b[j].w;
                }
            }
        }
        __syncthreads();
    }
#pragma unroll
    for (int r = 0; r < 8; ++r) {
        int gr = blockRow + row0 + r;
        if (gr < N) {
            float dsc = dis[gr];
            ushort4 hb;
            hb.x = f2bf(acc[r][0] * dsc); hb.y = f2bf(acc[r][1] * dsc);
            hb.z = f2bf(acc[r][2] * dsc); hb.w = f2bf(acc[r][3] * dsc);
            *(ushort4*)&Hbs[(size_t)gr * 64 + c0] = hb;
        }
    }
}

// ------- gather-aggregate: wave per 4 nodes, 2 edges per wave-instruction -------
// Lane layout: l = lane&31 handles features {2l, 2l+1} (one dword of the bf16 row);
// group g = lane>>5 handles edge j+g. Group partials combined via shfl_xor(32).
#define GNODE2(ACC, RA, RB)                                                    \
    {                                                                          \
        int j0 = max(RA - base, 0);                                            \
        int j1 = min(RB - base, cnt);                                          \
        int j = j0;                                                            \
        for (; j + 4 <= j1; j += 4) {                                          \
            unsigned o1 = __shfl(eoff, j + g, 64);                             \
            unsigned o2 = __shfl(eoff, j + 2 + g, 64);                         \
            unsigned d1 = *(const unsigned*)(hbase + o1);                      \
            unsigned d2 = *(const unsigned*)(hbase + o2);                      \
            ACC.x += __uint_as_float(d1 << 16);                                \
            ACC.y += __uint_as_float(d1 & 0xFFFF0000u);                        \
            ACC.x += __uint_as_float(d2 << 16);                                \
            ACC.y += __uint_as_float(d2 & 0xFFFF0000u);                        \
        }                                                                      \
        for (; j < j1; j += 2) {                                               \
            int idx = j + g;                                                   \
            bool valid = idx < j1;                                             \
            unsigned o = __shfl(eoff, valid ? idx : j0, 64);                   \
            unsigned d = *(const unsigned*)(hbase + o);                        \
            d = valid ? d : 0u;                                                \
            ACC.x += __uint_as_float(d << 16);                                 \
            ACC.y += __uint_as_float(d & 0xFFFF0000u);                         \
        }                                                                      \
    }

__global__ __launch_bounds__(256) void k_gather64(const unsigned short* __restrict__ Hbs,
                                                  const int* __restrict__ esrc,
                                                  const int* __restrict__ rowStart,
                                                  const float* __restrict__ dis,
                                                  const float* __restrict__ b,
                                                  float* __restrict__ out,
                                                  int N, int doRelu) {
    int lane = threadIdx.x & 63;
    int l = lane & 31;
    int g = lane >> 5;
    int wave = (blockIdx.x * 256 + threadIdx.x) >> 6;
    int g0 = wave * 4;
    if (g0 >= N) return;
    const char* hbase = (const char*)Hbs + l * 4;   // dword column of each row

    int rb = rowStart[min(g0 + lane, N)];
    int R0 = __shfl(rb, 0, 64), R1 = __shfl(rb, 1, 64);
    int R2 = __shfl(rb, 2, 64), R3 = __shfl(rb, 3, 64);
    int R4 = __shfl(rb, 4, 64);
    float dv = dis[min(g0 + lane, N - 1)];
    float d0 = __shfl(dv, 0, 64), d1 = __shfl(dv, 1, 64);
    float d2 = __shfl(dv, 2, 64), d3 = __shfl(dv, 3, 64);
    float2 bl = ((const float2*)b)[l];

    // self seeds: group 0 seeds nodes g0,g0+1; group 1 seeds g0+2,g0+3
    float2 a0 = {0.f, 0.f}, a1 = {0.f, 0.f}, a2 = {0.f, 0.f}, a3 = {0.f, 0.f};
    {
        int n0 = (g == 0) ? g0 : min(g0 + 2, N - 1);
        int n1 = (g == 0) ? min(g0 + 1, N - 1) : min(g0 + 3, N - 1);
        unsigned s0 = *(const unsigned*)(hbase + (size_t)n0 * 128);
        unsigned s1 = *(const unsigned*)(hbase + (size_t)n1 * 128);
        float2 f0 = {__uint_as_float(s0 << 16), __uint_as_float(s0 & 0xFFFF0000u)};
        float2 f1 = {__uint_as_float(s1 << 16), __uint_as_float(s1 & 0xFFFF0000u)};
        if (g == 0) { a0 = f0; a1 = f1; } else { a2 = f0; a3 = f1; }
    }

    for (int base = R0; base < R4; base += 64) {
        int cnt = min(64, R4 - base);
        unsigned eoff = (lane < cnt) ? (unsigned)esrc[base + lane] : 0u;
        GNODE2(a0, R0, R1)
        GNODE2(a1, R1, R2)
        GNODE2(a2, R2, R3)
        GNODE2(a3, R3, R4)
    }

    // combine group halves
    a0.x += __shfl_xor(a0.x, 32, 64); a0.y += __shfl_xor(a0.y, 32, 64);
    a1.x += __shfl_xor(a1.x, 32, 64); a1.y += __shfl_xor(a1.y, 32, 64);
    a2.x += __shfl_xor(a2.x, 32, 64); a2.y += __shfl_xor(a2.y, 32, 64);
    a3.x += __shfl_xor(a3.x, 32, 64); a3.y += __shfl_xor(a3.y, 32, 64);

    float2 v0 = {a0.x * d0 + bl.x, a0.y * d0 + bl.y};
    float2 v1 = {a1.x * d1 + bl.x, a1.y * d1 + bl.y};
    float2 v2 = {a2.x * d2 + bl.x, a2.y * d2 + bl.y};
    float2 v3 = {a3.x * d3 + bl.x, a3.y * d3 + bl.y};
    if (doRelu) {
        v0.x = fmaxf(v0.x, 0.f); v0.y = fmaxf(v0.y, 0.f);
        v1.x = fmaxf(v1.x, 0.f); v1.y = fmaxf(v1.y, 0.f);
        v2.x = fmaxf(v2.x, 0.f); v2.y = fmaxf(v2.y, 0.f);
        v3.x = fmaxf(v3.x, 0.f); v3.y = fmaxf(v3.y, 0.f);
    }
    if (g == 0) {
        ((float2*)(out + (size_t)g0 * 64))[l] = v0;
        if (g0 + 1 < N) ((float2*)(out + (size_t)(g0 + 1) * 64))[l] = v1;
    } else {
        if (g0 + 2 < N) ((float2*)(out + (size_t)(g0 + 2) * 64))[l] = v2;
        if (g0 + 3 < N) ((float2*)(out + (size_t)(g0 + 3) * 64))[l] = v3;
    }
}

// ---------------- layer 3: col = H.W3 ; colS = col*dis ; out = col*dis^2 + b3 --------
__global__ __launch_bounds__(256) void k_mm1col(const float* __restrict__ H,
                                                const float* __restrict__ W3,
                                                const float* __restrict__ b3,
                                                const float* __restrict__ dis,
                                                float* __restrict__ colS,
                                                float* __restrict__ out, int N) {
    int lane = threadIdx.x & 63;
    int node = (blockIdx.x * 256 + threadIdx.x) >> 6;
    if (node >= N) return;
    float v = H[(size_t)node * 64 + lane] * W3[lane];
#pragma unroll
    for (int off = 32; off >= 1; off >>= 1) v += __shfl_down(v, off, 64);
    if (lane == 0) {
        float d = dis[node];
        colS[node] = v * d;
        out[node] = v * d * d + b3[0];
    }
}

// out[i] += dis[i] * sum colS[esrc>>7]
__global__ __launch_bounds__(256) void k_gather1(const float* __restrict__ colS,
                                                 const int* __restrict__ esrc,
                                                 const int* __restrict__ rowStart,
                                                 const float* __restrict__ dis,
                                                 float* __restrict__ out, int N) {
    int i = blockIdx.x * 256 + threadIdx.x;
    if (i >= N) return;
    int r0 = rowStart[i], r1 = rowStart[i + 1];
    float acc = 0.0f;
    for (int e = r0; e < r1; ++e) acc += colS[((unsigned)esrc[e]) >> 7];
    out[i] += acc * dis[i];
}

extern "C" void kernel_launch(void* const* d_in, const int* in_sizes, int n_in,
                              void* d_out, int out_size, void* d_ws, size_t ws_size,
                              hipStream_t stream) {
    const float* x  = (const float*)d_in[0];
    const int*   ei = (const int*)d_in[1];
    const float* W1 = (const float*)d_in[2];
    const float* b1 = (const float*)d_in[3];
    const float* W2 = (const float*)d_in[4];
    const float* b2 = (const float*)d_in[5];
    const float* W3 = (const float*)d_in[6];
    const float* b3 = (const float*)d_in[7];
    float* out = (float*)d_out;

    const int N = in_sizes[0] / IN_DIM;     // 100000
    const int E = in_sizes[1] / 2;          // 1600000
    const int* src = ei;
    const int* dst = ei + E;
    const int NC = (N + 255) >> 8;          // 391 coarse buckets

    // ---- workspace layout ----
    char* w = (char*)d_ws;
    auto alloc = [&](size_t bytes) {
        char* p = w;
        w += (bytes + 1023) & ~(size_t)1023;
        return p;
    };
    float*          dis        = (float*)alloc((size_t)N * 4);
    float*          bufB       = (float*)alloc((size_t)N * 64 * 4);   // layer-1 out
    float*          bufC       = (float*)alloc((size_t)N * 64 * 4);   // layer-2 out
    unsigned short* Hbs        = (unsigned short*)alloc((size_t)N * 64 * 2);
    float*          colS       = (float*)alloc((size_t)N * 4);
    int*            rowStart   = (int*)alloc((size_t)(N + 1) * 4);
    int*            cursorC    = (int*)alloc((size_t)MAXC * 4);
    int*            coarseStart= (int*)alloc((size_t)(MAXC + 1) * 4);
    int*            esrc       = (int*)alloc((size_t)E * 4);
    int*            tmp1       = (int*)alloc((size_t)MAXC * CAP * 4);

    const int NB_N  = (N + 255) / 256;
    const int NB_MM = (N + 127) / 128;
    const int NB_WV = (N * 64 + 255) / 256;
    const int NB_G4 = ((N + 3) / 4 * 64 + 255) / 256;   // 4 nodes per wave
    const int NB_P  = (E + EPB - 1) / EPB;

    // ---- partition-driven CSR + degrees (no pre-histogram pass) ----
    hipMemsetAsync(cursorC, 0, (size_t)MAXC * sizeof(int), stream);
    k_part1<<<NB_P, 256, 0, stream>>>(src, dst, cursorC, tmp1, E, NC);
    k_cscan<<<1, 512, 0, stream>>>(cursorC, coarseStart, rowStart, NC, N, E);
    k_degplace<<<NC, 256, 0, stream>>>(tmp1, cursorC, coarseStart, dis, rowStart, esrc, N);

    // ---- layer 1 ----
    k_mmrt<IN_DIM><<<NB_MM, 256, 0, stream>>>(x, W1, dis, Hbs, N);
    k_gather64<<<NB_G4, 256, 0, stream>>>(Hbs, esrc, rowStart, dis, b1, bufB, N, 1);

    // ---- layer 2 ----
    k_mmrt<HID><<<NB_MM, 256, 0, stream>>>(bufB, W2, dis, Hbs, N);
    k_gather64<<<NB_G4, 256, 0, stream>>>(Hbs, esrc, rowStart, dis, b2, bufC, N, 1);

    // ---- layer 3 (OUT_DIM = 1) ----
    k_mm1col<<<NB_WV, 256, 0, stream>>>(bufC, W3, b3, dis, colS, out, N);
    k_gather1<<<NB_N, 256, 0, stream>>>(colS, esrc, rowStart, dis, out, N);
}

// Round 11
// 279.996 us; speedup vs baseline: 5.4898x; 1.0678x over previous
//
#include <hip/hip_runtime.h>

#define IN_DIM 128
#define HID 64
#define MAXC 400            // >= ceil(N/256); N=100000 -> 391 coarse buckets
#define EPB 8192
#define CAP 6144            // padded bucket capacity (mean 4096, 5-sigma ~4420)

// ---- bf16 helpers (RNE) ----
static __device__ __forceinline__ unsigned short f2bf(float f) {
    unsigned u = __float_as_uint(f);
    u += 0x7FFF + ((u >> 16) & 1);
    return (unsigned short)(u >> 16);
}
static __device__ __forceinline__ float bf2f(unsigned short h) {
    return __uint_as_float((unsigned)h << 16);
}

typedef short bf16x8 __attribute__((ext_vector_type(8)));
typedef float f32x4 __attribute__((ext_vector_type(4)));

// ---- pass 1: partition into padded coarse-bucket regions (no pre-scan needed) ----
// tmp1[cb*CAP + slot] = src | (dloc << 17), dloc = dst & 255 ; cursorC[cb] = count
__global__ __launch_bounds__(256) void k_part1(const int* __restrict__ src,
                                               const int* __restrict__ dst,
                                               int* __restrict__ cursorC,
                                               int* __restrict__ tmp1,
                                               int E, int NC) {
    __shared__ int bcnt[MAXC];
    __shared__ int bbase[MAXC];
    int tid = threadIdx.x;
    int e0 = blockIdx.x * EPB;
    int e1 = min(e0 + EPB, E);
    for (int i = tid; i < NC; i += 256) bcnt[i] = 0;
    __syncthreads();
    for (int e = e0 + tid; e < e1; e += 256) atomicAdd(&bcnt[dst[e] >> 8], 1);
    __syncthreads();
    for (int i = tid; i < NC; i += 256) {
        int c = bcnt[i];
        bbase[i] = c ? atomicAdd(&cursorC[i], c) : 0;
    }
    __syncthreads();
    for (int i = tid; i < NC; i += 256) bcnt[i] = 0;
    __syncthreads();
    for (int e = e0 + tid; e < e1; e += 256) {
        int s = src[e], d = dst[e];
        int cb = d >> 8;
        int slot = bbase[cb] + atomicAdd(&bcnt[cb], 1);
        tmp1[(size_t)cb * CAP + slot] = s | ((d & 255) << 17);
    }
}

// ---- single-block scan over bucket counts -> global CSR bases ----
__global__ __launch_bounds__(512) void k_cscan(const int* __restrict__ cursorC,
                                               int* __restrict__ coarseStart,
                                               int* __restrict__ rowStart,
                                               int NC, int N, int E) {
    __shared__ int tmp[512];
    int t = threadIdx.x;
    int v = (t < NC) ? cursorC[t] : 0;
    tmp[t] = v;
    __syncthreads();
    for (int off = 1; off < 512; off <<= 1) {
        int a = (t >= off) ? tmp[t - off] : 0;
        __syncthreads();
        tmp[t] += a;
        __syncthreads();
    }
    int excl = tmp[t] - v;
    if (t < NC) coarseStart[t] = excl;
    if (t == NC - 1) coarseStart[NC] = excl + v;   // == E
    if (t == 0) rowStart[N] = E;
}

// ---- pass 2 (fused): per-bucket degree->dis/rowStart, then place into CSR ----
// esrc holds BYTE offsets (s*128) for the gather's dword addressing.
__global__ __launch_bounds__(256) void k_degplace(const int* __restrict__ tmp1,
                                                  const int* __restrict__ cursorC,
                                                  const int* __restrict__ coarseStart,
                                                  float* __restrict__ dis,
                                                  int* __restrict__ rowStart,
                                                  int* __restrict__ esrc, int N) {
    __shared__ int hist[256];
    __shared__ int scn[256];
    __shared__ int cur[256];
    int tid = threadIdx.x;
    int cb = blockIdx.x;
    int node0 = cb << 8;
    const int cnt = cursorC[cb];
    const size_t bp = (size_t)cb * CAP;
    const int g0 = coarseStart[cb];
    hist[tid] = 0;
    __syncthreads();
    for (int i = tid; i < cnt; i += 256)
        atomicAdd(&hist[((unsigned)tmp1[bp + i]) >> 17], 1);
    __syncthreads();
    int v = hist[tid];
    scn[tid] = v;
    __syncthreads();
    for (int off = 1; off < 256; off <<= 1) {
        int a = (tid >= off) ? scn[tid - off] : 0;
        __syncthreads();
        scn[tid] += a;
        __syncthreads();
    }
    int myStart = g0 + scn[tid] - v;
    cur[tid] = myStart;
    int node = node0 + tid;
    if (node < N) {
        dis[node] = rsqrtf((float)v + 1.0f);
        rowStart[node] = myStart;
    }
    __syncthreads();
    for (int i = tid; i < cnt; i += 256) {
        int pk = tmp1[bp + i];
        int dl = ((unsigned)pk) >> 17;
        int pos = atomicAdd(&cur[dl], 1);
        esrc[pos] = (pk & 0x1FFFF) << 7;     // byte offset of bf16 row
    }
}

// ------- MFMA transform: Hbs[N,64] = bf16( (X[N,K] @ W[K,64]) * dis[row] ) -------
// block = 4 waves = 64 rows; wave = 16 rows x 64 cols (4 n-tiles of 16).
// A frag: lane holds X[row=base+(lane&15)][k0 + (lane>>4)*8 + j], j=0..7 (cvt fp32->bf16).
// B frag: Wt[n][k] staged bf16 in LDS (pad K+8).  D: col=lane&15, row=(lane>>4)*4+reg.
template <int K>
__global__ __launch_bounds__(256) void k_mmx(const float* __restrict__ X,
                                             const float* __restrict__ W,
                                             const float* __restrict__ dis,
                                             unsigned short* __restrict__ Hbs, int N) {
    constexpr int WP = K + 8;                 // multiple of 8 -> 16B-aligned frags
    __shared__ unsigned short Wt[64 * WP];
    const int tid = threadIdx.x;
    for (int i = tid; i < K * 64; i += 256) {
        int k = i >> 6, n = i & 63;
        Wt[n * WP + k] = f2bf(W[i]);
    }
    __syncthreads();
    const int lane = tid & 63;
    const int m16 = lane & 15;
    const int quad = lane >> 4;
    const int rowBase = blockIdx.x * 64 + (tid >> 6) * 16;
    const int rowc = min(rowBase + m16, N - 1);

    f32x4 acc0 = {0.f, 0.f, 0.f, 0.f};
    f32x4 acc1 = acc0, acc2 = acc0, acc3 = acc0;
    const float* xrow = X + (size_t)rowc * K;
#pragma unroll
    for (int k0 = 0; k0 < K; k0 += 32) {
        const float* xp = xrow + k0 + quad * 8;
        float4 xa = *(const float4*)xp;
        float4 xb = *(const float4*)(xp + 4);
        bf16x8 af;
        af[0] = (short)f2bf(xa.x); af[1] = (short)f2bf(xa.y);
        af[2] = (short)f2bf(xa.z); af[3] = (short)f2bf(xa.w);
        af[4] = (short)f2bf(xb.x); af[5] = (short)f2bf(xb.y);
        af[6] = (short)f2bf(xb.z); af[7] = (short)f2bf(xb.w);
        const unsigned short* wp = &Wt[m16 * WP + k0 + quad * 8];
        bf16x8 b0 = *(const bf16x8*)(wp);
        bf16x8 b1 = *(const bf16x8*)(wp + 16 * WP);
        bf16x8 b2 = *(const bf16x8*)(wp + 32 * WP);
        bf16x8 b3 = *(const bf16x8*)(wp + 48 * WP);
        acc0 = __builtin_amdgcn_mfma_f32_16x16x32_bf16(af, b0, acc0, 0, 0, 0);
        acc1 = __builtin_amdgcn_mfma_f32_16x16x32_bf16(af, b1, acc1, 0, 0, 0);
        acc2 = __builtin_amdgcn_mfma_f32_16x16x32_bf16(af, b2, acc2, 0, 0, 0);
        acc3 = __builtin_amdgcn_mfma_f32_16x16x32_bf16(af, b3, acc3, 0, 0, 0);
    }
#pragma unroll
    for (int reg = 0; reg < 4; ++reg) {
        int r = rowBase + quad * 4 + reg;
        if (r < N) {
            float dsc = dis[r];
            unsigned short* hp = Hbs + (size_t)r * 64 + m16;
            hp[0]  = f2bf(acc0[reg] * dsc);
            hp[16] = f2bf(acc1[reg] * dsc);
            hp[32] = f2bf(acc2[reg] * dsc);
            hp[48] = f2bf(acc3[reg] * dsc);
        }
    }
}

// ------- gather-aggregate: wave per 4 nodes, 2 edges per wave-instruction -------
#define GNODE2(ACC, RA, RB)                                                    \
    {                                                                          \
        int j0 = max(RA - base, 0);                                            \
        int j1 = min(RB - base, cnt);                                          \
        int j = j0;                                                            \
        for (; j + 4 <= j1; j += 4) {                                          \
            unsigned o1 = __shfl(eoff, j + g, 64);                             \
            unsigned o2 = __shfl(eoff, j + 2 + g, 64);                         \
            unsigned d1 = *(const unsigned*)(hbase + o1);                      \
            unsigned d2 = *(const unsigned*)(hbase + o2);                      \
            ACC.x += __uint_as_float(d1 << 16);                                \
            ACC.y += __uint_as_float(d1 & 0xFFFF0000u);                        \
            ACC.x += __uint_as_float(d2 << 16);                                \
            ACC.y += __uint_as_float(d2 & 0xFFFF0000u);                        \
        }                                                                      \
        for (; j < j1; j += 2) {                                               \
            int idx = j + g;                                                   \
            bool valid = idx < j1;                                             \
            unsigned o = __shfl(eoff, valid ? idx : j0, 64);                   \
            unsigned d = *(const unsigned*)(hbase + o);                        \
            d = valid ? d : 0u;                                                \
            ACC.x += __uint_as_float(d << 16);                                 \
            ACC.y += __uint_as_float(d & 0xFFFF0000u);                         \
        }                                                                      \
    }

__global__ __launch_bounds__(256) void k_gather64(const unsigned short* __restrict__ Hbs,
                                                  const int* __restrict__ esrc,
                                                  const int* __restrict__ rowStart,
                                                  const float* __restrict__ dis,
                                                  const float* __restrict__ b,
                                                  float* __restrict__ out,
                                                  int N, int doRelu) {
    int lane = threadIdx.x & 63;
    int l = lane & 31;
    int g = lane >> 5;
    int wave = (blockIdx.x * 256 + threadIdx.x) >> 6;
    int g0 = wave * 4;
    if (g0 >= N) return;
    const char* hbase = (const char*)Hbs + l * 4;   // dword column of each row

    int rb = rowStart[min(g0 + lane, N)];
    int R0 = __shfl(rb, 0, 64), R1 = __shfl(rb, 1, 64);
    int R2 = __shfl(rb, 2, 64), R3 = __shfl(rb, 3, 64);
    int R4 = __shfl(rb, 4, 64);
    float dv = dis[min(g0 + lane, N - 1)];
    float d0 = __shfl(dv, 0, 64), d1 = __shfl(dv, 1, 64);
    float d2 = __shfl(dv, 2, 64), d3 = __shfl(dv, 3, 64);
    float2 bl = ((const float2*)b)[l];

    float2 a0 = {0.f, 0.f}, a1 = {0.f, 0.f}, a2 = {0.f, 0.f}, a3 = {0.f, 0.f};
    {
        int n0 = (g == 0) ? g0 : min(g0 + 2, N - 1);
        int n1 = (g == 0) ? min(g0 + 1, N - 1) : min(g0 + 3, N - 1);
        unsigned s0 = *(const unsigned*)(hbase + (size_t)n0 * 128);
        unsigned s1 = *(const unsigned*)(hbase + (size_t)n1 * 128);
        float2 f0 = {__uint_as_float(s0 << 16), __uint_as_float(s0 & 0xFFFF0000u)};
        float2 f1 = {__uint_as_float(s1 << 16), __uint_as_float(s1 & 0xFFFF0000u)};
        if (g == 0) { a0 = f0; a1 = f1; } else { a2 = f0; a3 = f1; }
    }

    for (int base = R0; base < R4; base += 64) {
        int cnt = min(64, R4 - base);
        unsigned eoff = (lane < cnt) ? (unsigned)esrc[base + lane] : 0u;
        GNODE2(a0, R0, R1)
        GNODE2(a1, R1, R2)
        GNODE2(a2, R2, R3)
        GNODE2(a3, R3, R4)
    }

    a0.x += __shfl_xor(a0.x, 32, 64); a0.y += __shfl_xor(a0.y, 32, 64);
    a1.x += __shfl_xor(a1.x, 32, 64); a1.y += __shfl_xor(a1.y, 32, 64);
    a2.x += __shfl_xor(a2.x, 32, 64); a2.y += __shfl_xor(a2.y, 32, 64);
    a3.x += __shfl_xor(a3.x, 32, 64); a3.y += __shfl_xor(a3.y, 32, 64);

    float2 v0 = {a0.x * d0 + bl.x, a0.y * d0 + bl.y};
    float2 v1 = {a1.x * d1 + bl.x, a1.y * d1 + bl.y};
    float2 v2 = {a2.x * d2 + bl.x, a2.y * d2 + bl.y};
    float2 v3 = {a3.x * d3 + bl.x, a3.y * d3 + bl.y};
    if (doRelu) {
        v0.x = fmaxf(v0.x, 0.f); v0.y = fmaxf(v0.y, 0.f);
        v1.x = fmaxf(v1.x, 0.f); v1.y = fmaxf(v1.y, 0.f);
        v2.x = fmaxf(v2.x, 0.f); v2.y = fmaxf(v2.y, 0.f);
        v3.x = fmaxf(v3.x, 0.f); v3.y = fmaxf(v3.y, 0.f);
    }
    if (g == 0) {
        ((float2*)(out + (size_t)g0 * 64))[l] = v0;
        if (g0 + 1 < N) ((float2*)(out + (size_t)(g0 + 1) * 64))[l] = v1;
    } else {
        if (g0 + 2 < N) ((float2*)(out + (size_t)(g0 + 2) * 64))[l] = v2;
        if (g0 + 3 < N) ((float2*)(out + (size_t)(g0 + 3) * 64))[l] = v3;
    }
}

// ---------------- layer 3: col = H.W3 ; colS = col*dis ; out = col*dis^2 + b3 --------
__global__ __launch_bounds__(256) void k_mm1col(const float* __restrict__ H,
                                                const float* __restrict__ W3,
                                                const float* __restrict__ b3,
                                                const float* __restrict__ dis,
                                                float* __restrict__ colS,
                                                float* __restrict__ out, int N) {
    int lane = threadIdx.x & 63;
    int node = (blockIdx.x * 256 + threadIdx.x) >> 6;
    if (node >= N) return;
    float v = H[(size_t)node * 64 + lane] * W3[lane];
#pragma unroll
    for (int off = 32; off >= 1; off >>= 1) v += __shfl_down(v, off, 64);
    if (lane == 0) {
        float d = dis[node];
        colS[node] = v * d;
        out[node] = v * d * d + b3[0];
    }
}

// out[i] += dis[i] * sum colS[esrc>>7]
__global__ __launch_bounds__(256) void k_gather1(const float* __restrict__ colS,
                                                 const int* __restrict__ esrc,
                                                 const int* __restrict__ rowStart,
                                                 const float* __restrict__ dis,
                                                 float* __restrict__ out, int N) {
    int i = blockIdx.x * 256 + threadIdx.x;
    if (i >= N) return;
    int r0 = rowStart[i], r1 = rowStart[i + 1];
    float acc = 0.0f;
    for (int e = r0; e < r1; ++e) acc += colS[((unsigned)esrc[e]) >> 7];
    out[i] += acc * dis[i];
}

extern "C" void kernel_launch(void* const* d_in, const int* in_sizes, int n_in,
                              void* d_out, int out_size, void* d_ws, size_t ws_size,
                              hipStream_t stream) {
    const float* x  = (const float*)d_in[0];
    const int*   ei = (const int*)d_in[1];
    const float* W1 = (const float*)d_in[2];
    const float* b1 = (const float*)d_in[3];
    const float* W2 = (const float*)d_in[4];
    const float* b2 = (const float*)d_in[5];
    const float* W3 = (const float*)d_in[6];
    const float* b3 = (const float*)d_in[7];
    float* out = (float*)d_out;

    const int N = in_sizes[0] / IN_DIM;     // 100000
    const int E = in_sizes[1] / 2;          // 1600000
    const int* src = ei;
    const int* dst = ei + E;
    const int NC = (N + 255) >> 8;          // 391 coarse buckets

    // ---- workspace layout ----
    char* w = (char*)d_ws;
    auto alloc = [&](size_t bytes) {
        char* p = w;
        w += (bytes + 1023) & ~(size_t)1023;
        return p;
    };
    float*          dis        = (float*)alloc((size_t)N * 4);
    float*          bufB       = (float*)alloc((size_t)N * 64 * 4);   // layer-1 out
    float*          bufC       = (float*)alloc((size_t)N * 64 * 4);   // layer-2 out
    unsigned short* Hbs        = (unsigned short*)alloc((size_t)N * 64 * 2);
    float*          colS       = (float*)alloc((size_t)N * 4);
    int*            rowStart   = (int*)alloc((size_t)(N + 1) * 4);
    int*            cursorC    = (int*)alloc((size_t)MAXC * 4);
    int*            coarseStart= (int*)alloc((size_t)(MAXC + 1) * 4);
    int*            esrc       = (int*)alloc((size_t)E * 4);
    int*            tmp1       = (int*)alloc((size_t)MAXC * CAP * 4);

    const int NB_N  = (N + 255) / 256;
    const int NB_MX = (N + 63) / 64;                    // MFMA transform blocks
    const int NB_WV = (N * 64 + 255) / 256;
    const int NB_G4 = ((N + 3) / 4 * 64 + 255) / 256;   // 4 nodes per wave
    const int NB_P  = (E + EPB - 1) / EPB;

    // ---- partition-driven CSR + degrees (no pre-histogram pass) ----
    hipMemsetAsync(cursorC, 0, (size_t)MAXC * sizeof(int), stream);
    k_part1<<<NB_P, 256, 0, stream>>>(src, dst, cursorC, tmp1, E, NC);
    k_cscan<<<1, 512, 0, stream>>>(cursorC, coarseStart, rowStart, NC, N, E);
    k_degplace<<<NC, 256, 0, stream>>>(tmp1, cursorC, coarseStart, dis, rowStart, esrc, N);

    // ---- layer 1 ----
    k_mmx<IN_DIM><<<NB_MX, 256, 0, stream>>>(x, W1, dis, Hbs, N);
    k_gather64<<<NB_G4, 256, 0, stream>>>(Hbs, esrc, rowStart, dis, b1, bufB, N, 1);

    // ---- layer 2 ----
    k_mmx<HID><<<NB_MX, 256, 0, stream>>>(bufB, W2, dis, Hbs, N);
    k_gather64<<<NB_G4, 256, 0, stream>>>(Hbs, esrc, rowStart, dis, b2, bufC, N, 1);

    // ---- layer 3 (OUT_DIM = 1) ----
    k_mm1col<<<NB_WV, 256, 0, stream>>>(bufC, W3, b3, dis, colS, out, N);
    k_gather1<<<NB_N, 256, 0, stream>>>(colS, esrc, rowStart, dis, out, N);
}

// Round 12
// 270.041 us; speedup vs baseline: 5.6921x; 1.0369x over previous
//
#include <hip/hip_runtime.h>

#define IN_DIM 128
#define HID 64
#define MAXC 400            // >= ceil(N/256); N=100000 -> 391 coarse buckets
#define EPB 2048            // edges per partition block (782 blocks -> real occupancy)
#define CAP 6144            // padded bucket capacity (mean 4096, 5-sigma ~4420)
#define DPT 1024            // degplace threads per block

// ---- bf16 helpers (RNE) ----
static __device__ __forceinline__ unsigned short f2bf(float f) {
    unsigned u = __float_as_uint(f);
    u += 0x7FFF + ((u >> 16) & 1);
    return (unsigned short)(u >> 16);
}

typedef short bf16x8 __attribute__((ext_vector_type(8)));
typedef float f32x4 __attribute__((ext_vector_type(4)));

// ---- pass 1: partition into padded coarse-bucket regions ----
// tmp1[cb*CAP + slot] = src | (dloc << 17), dloc = dst & 255 ; cursorC[cb] = count
__global__ __launch_bounds__(256) void k_part1(const int* __restrict__ src,
                                               const int* __restrict__ dst,
                                               int* __restrict__ cursorC,
                                               int* __restrict__ tmp1,
                                               int E, int NC) {
    __shared__ int bcnt[MAXC];
    __shared__ int bbase[MAXC];
    int tid = threadIdx.x;
    int e0 = blockIdx.x * EPB;
    int e1 = min(e0 + EPB, E);
    for (int i = tid; i < NC; i += 256) bcnt[i] = 0;
    __syncthreads();
    for (int e = e0 + tid; e < e1; e += 256) atomicAdd(&bcnt[dst[e] >> 8], 1);
    __syncthreads();
    for (int i = tid; i < NC; i += 256) {
        int c = bcnt[i];
        bbase[i] = c ? atomicAdd(&cursorC[i], c) : 0;
    }
    __syncthreads();
    for (int i = tid; i < NC; i += 256) bcnt[i] = 0;
    __syncthreads();
    for (int e = e0 + tid; e < e1; e += 256) {
        int s = src[e], d = dst[e];
        int cb = d >> 8;
        int slot = bbase[cb] + atomicAdd(&bcnt[cb], 1);
        tmp1[(size_t)cb * CAP + slot] = s | ((d & 255) << 17);
    }
}

// ---- single-block scan over bucket counts -> global CSR bases ----
__global__ __launch_bounds__(512) void k_cscan(const int* __restrict__ cursorC,
                                               int* __restrict__ coarseStart,
                                               int* __restrict__ rowStart,
                                               int NC, int N, int E) {
    __shared__ int tmp[512];
    int t = threadIdx.x;
    int v = (t < NC) ? cursorC[t] : 0;
    tmp[t] = v;
    __syncthreads();
    for (int off = 1; off < 512; off <<= 1) {
        int a = (t >= off) ? tmp[t - off] : 0;
        __syncthreads();
        tmp[t] += a;
        __syncthreads();
    }
    int excl = tmp[t] - v;
    if (t < NC) coarseStart[t] = excl;
    if (t == NC - 1) coarseStart[NC] = excl + v;   // == E
    if (t == 0) rowStart[N] = E;
}

// ---- pass 2 (fused): per-bucket degree->dis/rowStart, then place into CSR ----
// esrc holds BYTE offsets (s*128) for the gather's dword addressing.
__global__ __launch_bounds__(DPT) void k_degplace(const int* __restrict__ tmp1,
                                                  const int* __restrict__ cursorC,
                                                  const int* __restrict__ coarseStart,
                                                  float* __restrict__ dis,
                                                  int* __restrict__ rowStart,
                                                  int* __restrict__ esrc, int N) {
    __shared__ int hist[256];
    __shared__ int scn[256];
    __shared__ int cur[256];
    int tid = threadIdx.x;
    int cb = blockIdx.x;
    int node0 = cb << 8;
    const int cnt = cursorC[cb];
    const size_t bp = (size_t)cb * CAP;
    const int g0 = coarseStart[cb];
    if (tid < 256) hist[tid] = 0;
    __syncthreads();
    for (int i = tid; i < cnt; i += DPT)
        atomicAdd(&hist[((unsigned)tmp1[bp + i]) >> 17], 1);
    __syncthreads();
    int v = 0;
    if (tid < 256) { v = hist[tid]; scn[tid] = v; }
    __syncthreads();
    for (int off = 1; off < 256; off <<= 1) {
        int a = 0;
        if (tid < 256 && tid >= off) a = scn[tid - off];
        __syncthreads();
        if (tid < 256) scn[tid] += a;
        __syncthreads();
    }
    if (tid < 256) {
        int myStart = g0 + scn[tid] - v;
        cur[tid] = myStart;
        int node = node0 + tid;
        if (node < N) {
            dis[node] = rsqrtf((float)v + 1.0f);
            rowStart[node] = myStart;
        }
    }
    __syncthreads();
    for (int i = tid; i < cnt; i += DPT) {
        int pk = tmp1[bp + i];
        int dl = ((unsigned)pk) >> 17;
        int pos = atomicAdd(&cur[dl], 1);
        esrc[pos] = (pk & 0x1FFFF) << 7;     // byte offset of bf16 row
    }
}

// ------- MFMA transform: Hbs[N,64] = bf16( (X[N,K] @ W[K,64]) * dis[row] ) -------
// T = float (fp32 input, cvt) or unsigned short (bf16 input, direct).
template <int K, typename T>
__global__ __launch_bounds__(256) void k_mmx(const T* __restrict__ X,
                                             const float* __restrict__ W,
                                             const float* __restrict__ dis,
                                             unsigned short* __restrict__ Hbs, int N) {
    constexpr int WP = K + 8;                 // multiple of 8 -> 16B-aligned frags
    __shared__ unsigned short Wt[64 * WP];
    const int tid = threadIdx.x;
    for (int i = tid; i < K * 64; i += 256) {
        int k = i >> 6, n = i & 63;
        Wt[n * WP + k] = f2bf(W[i]);
    }
    __syncthreads();
    const int lane = tid & 63;
    const int m16 = lane & 15;
    const int quad = lane >> 4;
    const int rowBase = blockIdx.x * 64 + (tid >> 6) * 16;
    const int rowc = min(rowBase + m16, N - 1);

    f32x4 acc0 = {0.f, 0.f, 0.f, 0.f};
    f32x4 acc1 = acc0, acc2 = acc0, acc3 = acc0;
    const T* xrow = X + (size_t)rowc * K;
#pragma unroll
    for (int k0 = 0; k0 < K; k0 += 32) {
        bf16x8 af;
        if constexpr (sizeof(T) == 4) {
            const float* xp = (const float*)xrow + k0 + quad * 8;
            float4 xa = *(const float4*)xp;
            float4 xb = *(const float4*)(xp + 4);
            af[0] = (short)f2bf(xa.x); af[1] = (short)f2bf(xa.y);
            af[2] = (short)f2bf(xa.z); af[3] = (short)f2bf(xa.w);
            af[4] = (short)f2bf(xb.x); af[5] = (short)f2bf(xb.y);
            af[6] = (short)f2bf(xb.z); af[7] = (short)f2bf(xb.w);
        } else {
            af = *(const bf16x8*)((const unsigned short*)xrow + k0 + quad * 8);
        }
        const unsigned short* wp = &Wt[m16 * WP + k0 + quad * 8];
        bf16x8 b0 = *(const bf16x8*)(wp);
        bf16x8 b1 = *(const bf16x8*)(wp + 16 * WP);
        bf16x8 b2 = *(const bf16x8*)(wp + 32 * WP);
        bf16x8 b3 = *(const bf16x8*)(wp + 48 * WP);
        acc0 = __builtin_amdgcn_mfma_f32_16x16x32_bf16(af, b0, acc0, 0, 0, 0);
        acc1 = __builtin_amdgcn_mfma_f32_16x16x32_bf16(af, b1, acc1, 0, 0, 0);
        acc2 = __builtin_amdgcn_mfma_f32_16x16x32_bf16(af, b2, acc2, 0, 0, 0);
        acc3 = __builtin_amdgcn_mfma_f32_16x16x32_bf16(af, b3, acc3, 0, 0, 0);
    }
#pragma unroll
    for (int reg = 0; reg < 4; ++reg) {
        int r = rowBase + quad * 4 + reg;
        if (r < N) {
            float dsc = dis[r];
            unsigned short* hp = Hbs + (size_t)r * 64 + m16;
            hp[0]  = f2bf(acc0[reg] * dsc);
            hp[16] = f2bf(acc1[reg] * dsc);
            hp[32] = f2bf(acc2[reg] * dsc);
            hp[48] = f2bf(acc3[reg] * dsc);
        }
    }
}

// ------- gather-aggregate: wave per 4 nodes, 2 edges per wave-instruction -------
// MODE 1: out = relu row, stored bf16 (layer 1 -> feeds bf16 mmx)
// MODE 2: relu row, dot with W3, write colS[i] = dot*dis and out[i] = dot*dis^2 + b3
#define GNODE2(ACC, RA, RB)                                                    \
    {                                                                          \
        int j0 = max(RA - base, 0);                                            \
        int j1 = min(RB - base, cnt);                                          \
        int j = j0;                                                            \
        for (; j + 4 <= j1; j += 4) {                                          \
            unsigned o1 = __shfl(eoff, j + g, 64);                             \
            unsigned o2 = __shfl(eoff, j + 2 + g, 64);                         \
            unsigned d1 = *(const unsigned*)(hbase + o1);                      \
            unsigned d2 = *(const unsigned*)(hbase + o2);                      \
            ACC.x += __uint_as_float(d1 << 16);                                \
            ACC.y += __uint_as_float(d1 & 0xFFFF0000u);                        \
            ACC.x += __uint_as_float(d2 << 16);                                \
            ACC.y += __uint_as_float(d2 & 0xFFFF0000u);                        \
        }                                                                      \
        for (; j < j1; j += 2) {                                               \
            int idx = j + g;                                                   \
            bool valid = idx < j1;                                             \
            unsigned o = __shfl(eoff, valid ? idx : j0, 64);                   \
            unsigned d = *(const unsigned*)(hbase + o);                        \
            d = valid ? d : 0u;                                                \
            ACC.x += __uint_as_float(d << 16);                                 \
            ACC.y += __uint_as_float(d & 0xFFFF0000u);                         \
        }                                                                      \
    }

template <int MODE>
__global__ __launch_bounds__(256) void k_gather64(const unsigned short* __restrict__ Hbs,
                                                  const int* __restrict__ esrc,
                                                  const int* __restrict__ rowStart,
                                                  const float* __restrict__ dis,
                                                  const float* __restrict__ b,
                                                  unsigned short* __restrict__ outB,
                                                  const float* __restrict__ W3,
                                                  const float* __restrict__ b3,
                                                  float* __restrict__ colS,
                                                  float* __restrict__ outF,
                                                  int N) {
    int lane = threadIdx.x & 63;
    int l = lane & 31;
    int g = lane >> 5;
    int wave = (blockIdx.x * 256 + threadIdx.x) >> 6;
    int g0 = wave * 4;
    if (g0 >= N) return;
    const char* hbase = (const char*)Hbs + l * 4;   // dword column of each row

    int rb = rowStart[min(g0 + lane, N)];
    int R0 = __shfl(rb, 0, 64), R1 = __shfl(rb, 1, 64);
    int R2 = __shfl(rb, 2, 64), R3 = __shfl(rb, 3, 64);
    int R4 = __shfl(rb, 4, 64);
    float dv = dis[min(g0 + lane, N - 1)];
    float d0 = __shfl(dv, 0, 64), d1 = __shfl(dv, 1, 64);
    float d2 = __shfl(dv, 2, 64), d3 = __shfl(dv, 3, 64);
    float2 bl = ((const float2*)b)[l];

    float2 a0 = {0.f, 0.f}, a1 = {0.f, 0.f}, a2 = {0.f, 0.f}, a3 = {0.f, 0.f};
    {
        int n0 = (g == 0) ? g0 : min(g0 + 2, N - 1);
        int n1 = (g == 0) ? min(g0 + 1, N - 1) : min(g0 + 3, N - 1);
        unsigned s0 = *(const unsigned*)(hbase + (size_t)n0 * 128);
        unsigned s1 = *(const unsigned*)(hbase + (size_t)n1 * 128);
        float2 f0 = {__uint_as_float(s0 << 16), __uint_as_float(s0 & 0xFFFF0000u)};
        float2 f1 = {__uint_as_float(s1 << 16), __uint_as_float(s1 & 0xFFFF0000u)};
        if (g == 0) { a0 = f0; a1 = f1; } else { a2 = f0; a3 = f1; }
    }

    for (int base = R0; base < R4; base += 64) {
        int cnt = min(64, R4 - base);
        unsigned eoff = (lane < cnt) ? (unsigned)esrc[base + lane] : 0u;
        GNODE2(a0, R0, R1)
        GNODE2(a1, R1, R2)
        GNODE2(a2, R2, R3)
        GNODE2(a3, R3, R4)
    }

    a0.x += __shfl_xor(a0.x, 32, 64); a0.y += __shfl_xor(a0.y, 32, 64);
    a1.x += __shfl_xor(a1.x, 32, 64); a1.y += __shfl_xor(a1.y, 32, 64);
    a2.x += __shfl_xor(a2.x, 32, 64); a2.y += __shfl_xor(a2.y, 32, 64);
    a3.x += __shfl_xor(a3.x, 32, 64); a3.y += __shfl_xor(a3.y, 32, 64);

    float2 v0 = {fmaxf(a0.x * d0 + bl.x, 0.f), fmaxf(a0.y * d0 + bl.y, 0.f)};
    float2 v1 = {fmaxf(a1.x * d1 + bl.x, 0.f), fmaxf(a1.y * d1 + bl.y, 0.f)};
    float2 v2 = {fmaxf(a2.x * d2 + bl.x, 0.f), fmaxf(a2.y * d2 + bl.y, 0.f)};
    float2 v3 = {fmaxf(a3.x * d3 + bl.x, 0.f), fmaxf(a3.y * d3 + bl.y, 0.f)};

    if (MODE == 1) {
        // pack 2 features -> one dword, store bf16 rows
        unsigned p0 = (unsigned)f2bf(v0.x) | ((unsigned)f2bf(v0.y) << 16);
        unsigned p1 = (unsigned)f2bf(v1.x) | ((unsigned)f2bf(v1.y) << 16);
        unsigned p2 = (unsigned)f2bf(v2.x) | ((unsigned)f2bf(v2.y) << 16);
        unsigned p3 = (unsigned)f2bf(v3.x) | ((unsigned)f2bf(v3.y) << 16);
        unsigned* ob = (unsigned*)outB;
        if (g == 0) {
            ob[(size_t)g0 * 32 + l] = p0;
            if (g0 + 1 < N) ob[(size_t)(g0 + 1) * 32 + l] = p1;
        } else {
            if (g0 + 2 < N) ob[(size_t)(g0 + 2) * 32 + l] = p2;
            if (g0 + 3 < N) ob[(size_t)(g0 + 3) * 32 + l] = p3;
        }
    } else {
        // dot with W3 across the 64-feature row (halves hold identical copies)
        float2 w3 = ((const float2*)W3)[l];
        float t0 = v0.x * w3.x + v0.y * w3.y;
        float t1 = v1.x * w3.x + v1.y * w3.y;
        float t2 = v2.x * w3.x + v2.y * w3.y;
        float t3 = v3.x * w3.x + v3.y * w3.y;
#pragma unroll
        for (int off = 1; off <= 16; off <<= 1) {
            t0 += __shfl_xor(t0, off, 64);
            t1 += __shfl_xor(t1, off, 64);
            t2 += __shfl_xor(t2, off, 64);
            t3 += __shfl_xor(t3, off, 64);
        }
        if (lane == 0) {
            float bb = b3[0];
            colS[g0] = t0 * d0;
            outF[g0] = t0 * d0 * d0 + bb;
            if (g0 + 1 < N) { colS[g0 + 1] = t1 * d1; outF[g0 + 1] = t1 * d1 * d1 + bb; }
            if (g0 + 2 < N) { colS[g0 + 2] = t2 * d2; outF[g0 + 2] = t2 * d2 * d2 + bb; }
            if (g0 + 3 < N) { colS[g0 + 3] = t3 * d3; outF[g0 + 3] = t3 * d3 * d3 + bb; }
        }
    }
}

// out[i] += dis[i] * sum colS[esrc>>7]
__global__ __launch_bounds__(256) void k_gather1(const float* __restrict__ colS,
                                                 const int* __restrict__ esrc,
                                                 const int* __restrict__ rowStart,
                                                 const float* __restrict__ dis,
                                                 float* __restrict__ out, int N) {
    int i = blockIdx.x * 256 + threadIdx.x;
    if (i >= N) return;
    int r0 = rowStart[i], r1 = rowStart[i + 1];
    float acc = 0.0f;
    for (int e = r0; e < r1; ++e) acc += colS[((unsigned)esrc[e]) >> 7];
    out[i] += acc * dis[i];
}

extern "C" void kernel_launch(void* const* d_in, const int* in_sizes, int n_in,
                              void* d_out, int out_size, void* d_ws, size_t ws_size,
                              hipStream_t stream) {
    const float* x  = (const float*)d_in[0];
    const int*   ei = (const int*)d_in[1];
    const float* W1 = (const float*)d_in[2];
    const float* b1 = (const float*)d_in[3];
    const float* W2 = (const float*)d_in[4];
    const float* b2 = (const float*)d_in[5];
    const float* W3 = (const float*)d_in[6];
    const float* b3 = (const float*)d_in[7];
    float* out = (float*)d_out;

    const int N = in_sizes[0] / IN_DIM;     // 100000
    const int E = in_sizes[1] / 2;          // 1600000
    const int* src = ei;
    const int* dst = ei + E;
    const int NC = (N + 255) >> 8;          // 391 coarse buckets

    // ---- workspace layout ----
    char* w = (char*)d_ws;
    auto alloc = [&](size_t bytes) {
        char* p = w;
        w += (bytes + 1023) & ~(size_t)1023;
        return p;
    };
    float*          dis        = (float*)alloc((size_t)N * 4);
    unsigned short* Hbs        = (unsigned short*)alloc((size_t)N * 64 * 2);
    unsigned short* Hb1        = (unsigned short*)alloc((size_t)N * 64 * 2);  // layer-1 out, bf16
    float*          colS       = (float*)alloc((size_t)N * 4);
    int*            rowStart   = (int*)alloc((size_t)(N + 1) * 4);
    int*            cursorC    = (int*)alloc((size_t)MAXC * 4);
    int*            coarseStart= (int*)alloc((size_t)(MAXC + 1) * 4);
    int*            esrc       = (int*)alloc((size_t)E * 4);
    int*            tmp1       = (int*)alloc((size_t)MAXC * CAP * 4);

    const int NB_N  = (N + 255) / 256;
    const int NB_MX = (N + 63) / 64;                    // MFMA transform blocks
    const int NB_G4 = ((N + 3) / 4 * 64 + 255) / 256;   // 4 nodes per wave
    const int NB_P  = (E + EPB - 1) / EPB;              // 782 partition blocks

    // ---- partition-driven CSR + degrees ----
    hipMemsetAsync(cursorC, 0, (size_t)MAXC * sizeof(int), stream);
    k_part1<<<NB_P, 256, 0, stream>>>(src, dst, cursorC, tmp1, E, NC);
    k_cscan<<<1, 512, 0, stream>>>(cursorC, coarseStart, rowStart, NC, N, E);
    k_degplace<<<NC, DPT, 0, stream>>>(tmp1, cursorC, coarseStart, dis, rowStart, esrc, N);

    // ---- layer 1: mmx fp32->bf16, gather -> bf16 rows ----
    k_mmx<IN_DIM, float><<<NB_MX, 256, 0, stream>>>(x, W1, dis, Hbs, N);
    k_gather64<1><<<NB_G4, 256, 0, stream>>>(Hbs, esrc, rowStart, dis, b1,
                                             Hb1, nullptr, nullptr, nullptr, nullptr, N);

    // ---- layer 2: mmx bf16 input, gather fused with W3 dot (layer 3 transform) ----
    k_mmx<HID, unsigned short><<<NB_MX, 256, 0, stream>>>(Hb1, W2, dis, Hbs, N);
    k_gather64<2><<<NB_G4, 256, 0, stream>>>(Hbs, esrc, rowStart, dis, b2,
                                             nullptr, W3, b3, colS, out, N);

    // ---- layer 3 aggregation ----
    k_gather1<<<NB_N, 256, 0, stream>>>(colS, esrc, rowStart, dis, out, N);
}

// Round 13
// 262.708 us; speedup vs baseline: 5.8510x; 1.0279x over previous
//
#include <hip/hip_runtime.h>

#define IN_DIM 128
#define HID 64
#define MAXC 400            // >= ceil(N/256); N=100000 -> 391 coarse buckets
#define MAXB 256            // >= NBLK = ceil(E/EPB) = 196
#define EPB 8192
#define DPT 1024            // degplace threads per block

// ---- bf16 helpers (RNE) ----
static __device__ __forceinline__ unsigned short f2bf(float f) {
    unsigned u = __float_as_uint(f);
    u += 0x7FFF + ((u >> 16) & 1);
    return (unsigned short)(u >> 16);
}

typedef short bf16x8 __attribute__((ext_vector_type(8)));
typedef float f32x4 __attribute__((ext_vector_type(4)));

// ---- pass 0: per-block bucket histogram -> hmat[blk][cb] (coalesced row) ----
__global__ __launch_bounds__(256) void k_hist2(const int* __restrict__ dst,
                                               int* __restrict__ hmat, int E, int NC) {
    __shared__ int h[MAXC];
    int tid = threadIdx.x, blk = blockIdx.x;
    for (int i = tid; i < NC; i += 256) h[i] = 0;
    __syncthreads();
    int e0 = blk * EPB, e1 = min(e0 + EPB, E);
    for (int e = e0 + tid; e < e1; e += 256) atomicAdd(&h[dst[e] >> 8], 1);
    __syncthreads();
    for (int i = tid; i < NC; i += 256) hmat[blk * MAXC + i] = h[i];
}

// ---- per-bucket exclusive scan across blocks (in-place) + bucket totals ----
__global__ __launch_bounds__(256) void k_bktscan(int* __restrict__ hmat,
                                                 int* __restrict__ bktTotal,
                                                 int NBLK, int NC) {
    __shared__ int tmp[256];
    int cb = blockIdx.x;
    int t = threadIdx.x;
    int v = (t < NBLK) ? hmat[t * MAXC + cb] : 0;
    tmp[t] = v;
    __syncthreads();
    for (int off = 1; off < 256; off <<= 1) {
        int a = (t >= off) ? tmp[t - off] : 0;
        __syncthreads();
        tmp[t] += a;
        __syncthreads();
    }
    if (t < NBLK) hmat[t * MAXC + cb] = tmp[t] - v;   // exclusive prefix within bucket
    if (t == 255) bktTotal[cb] = tmp[255];
}

// ---- single-block scan over bucket totals -> coarseStart ----
__global__ __launch_bounds__(512) void k_cscan(const int* __restrict__ bktTotal,
                                               int* __restrict__ coarseStart,
                                               int* __restrict__ rowStart,
                                               int NC, int N, int E) {
    __shared__ int tmp[512];
    int t = threadIdx.x;
    int v = (t < NC) ? bktTotal[t] : 0;
    tmp[t] = v;
    __syncthreads();
    for (int off = 1; off < 512; off <<= 1) {
        int a = (t >= off) ? tmp[t - off] : 0;
        __syncthreads();
        tmp[t] += a;
        __syncthreads();
    }
    int excl = tmp[t] - v;
    if (t < NC) coarseStart[t] = excl;
    if (t == NC - 1) coarseStart[NC] = excl + v;   // == E
    if (t == 0) rowStart[N] = E;
}

// ---- pass 1: deterministic placement into dense coarse-sorted array ----
// tmp1[pos] = src | (dloc << 17); no global atomics.
__global__ __launch_bounds__(256) void k_part1(const int* __restrict__ src,
                                               const int* __restrict__ dst,
                                               const int* __restrict__ hmat,
                                               const int* __restrict__ coarseStart,
                                               int* __restrict__ tmp1,
                                               int E, int NC) {
    __shared__ int bcnt[MAXC];
    __shared__ int bbase[MAXC];
    int tid = threadIdx.x, blk = blockIdx.x;
    for (int i = tid; i < NC; i += 256) {
        bcnt[i] = 0;
        bbase[i] = coarseStart[i] + hmat[blk * MAXC + i];   // coalesced
    }
    __syncthreads();
    int e0 = blk * EPB, e1 = min(e0 + EPB, E);
    for (int e = e0 + tid; e < e1; e += 256) {
        int s = src[e], d = dst[e];
        int cb = d >> 8;
        int slot = bbase[cb] + atomicAdd(&bcnt[cb], 1);
        tmp1[slot] = s | ((d & 255) << 17);
    }
}

// ---- pass 2 (fused): per-bucket degree->dis/rowStart, then place into CSR ----
// esrc holds BYTE offsets (s*128) for the gather's dword addressing.
__global__ __launch_bounds__(DPT) void k_degplace(const int* __restrict__ tmp1,
                                                  const int* __restrict__ coarseStart,
                                                  float* __restrict__ dis,
                                                  int* __restrict__ rowStart,
                                                  int* __restrict__ esrc, int N) {
    __shared__ int hist[256];
    __shared__ int scn[256];
    __shared__ int cur[256];
    int tid = threadIdx.x;
    int cb = blockIdx.x;
    int node0 = cb << 8;
    const int r0 = coarseStart[cb], r1 = coarseStart[cb + 1];
    if (tid < 256) hist[tid] = 0;
    __syncthreads();
    for (int i = r0 + tid; i < r1; i += DPT)
        atomicAdd(&hist[((unsigned)tmp1[i]) >> 17], 1);
    __syncthreads();
    int v = 0;
    if (tid < 256) { v = hist[tid]; scn[tid] = v; }
    __syncthreads();
    for (int off = 1; off < 256; off <<= 1) {
        int a = 0;
        if (tid < 256 && tid >= off) a = scn[tid - off];
        __syncthreads();
        if (tid < 256) scn[tid] += a;
        __syncthreads();
    }
    if (tid < 256) {
        int myStart = r0 + scn[tid] - v;
        cur[tid] = myStart;
        int node = node0 + tid;
        if (node < N) {
            dis[node] = rsqrtf((float)v + 1.0f);
            rowStart[node] = myStart;
        }
    }
    __syncthreads();
    for (int i = r0 + tid; i < r1; i += DPT) {
        int pk = tmp1[i];
        int dl = ((unsigned)pk) >> 17;
        int pos = atomicAdd(&cur[dl], 1);
        esrc[pos] = (pk & 0x1FFFF) << 7;     // byte offset of bf16 row
    }
}

// ------- MFMA transform: Hbs[N,64] = bf16( (X[N,K] @ W[K,64]) * dis[row] ) -------
template <int K, typename T>
__global__ __launch_bounds__(256) void k_mmx(const T* __restrict__ X,
                                             const float* __restrict__ W,
                                             const float* __restrict__ dis,
                                             unsigned short* __restrict__ Hbs, int N) {
    constexpr int WP = K + 8;
    __shared__ unsigned short Wt[64 * WP];
    const int tid = threadIdx.x;
    for (int i = tid; i < K * 64; i += 256) {
        int k = i >> 6, n = i & 63;
        Wt[n * WP + k] = f2bf(W[i]);
    }
    __syncthreads();
    const int lane = tid & 63;
    const int m16 = lane & 15;
    const int quad = lane >> 4;
    const int rowBase = blockIdx.x * 64 + (tid >> 6) * 16;
    const int rowc = min(rowBase + m16, N - 1);

    f32x4 acc0 = {0.f, 0.f, 0.f, 0.f};
    f32x4 acc1 = acc0, acc2 = acc0, acc3 = acc0;
    const T* xrow = X + (size_t)rowc * K;
#pragma unroll
    for (int k0 = 0; k0 < K; k0 += 32) {
        bf16x8 af;
        if constexpr (sizeof(T) == 4) {
            const float* xp = (const float*)xrow + k0 + quad * 8;
            float4 xa = *(const float4*)xp;
            float4 xb = *(const float4*)(xp + 4);
            af[0] = (short)f2bf(xa.x); af[1] = (short)f2bf(xa.y);
            af[2] = (short)f2bf(xa.z); af[3] = (short)f2bf(xa.w);
            af[4] = (short)f2bf(xb.x); af[5] = (short)f2bf(xb.y);
            af[6] = (short)f2bf(xb.z); af[7] = (short)f2bf(xb.w);
        } else {
            af = *(const bf16x8*)((const unsigned short*)xrow + k0 + quad * 8);
        }
        const unsigned short* wp = &Wt[m16 * WP + k0 + quad * 8];
        bf16x8 b0 = *(const bf16x8*)(wp);
        bf16x8 b1 = *(const bf16x8*)(wp + 16 * WP);
        bf16x8 b2 = *(const bf16x8*)(wp + 32 * WP);
        bf16x8 b3 = *(const bf16x8*)(wp + 48 * WP);
        acc0 = __builtin_amdgcn_mfma_f32_16x16x32_bf16(af, b0, acc0, 0, 0, 0);
        acc1 = __builtin_amdgcn_mfma_f32_16x16x32_bf16(af, b1, acc1, 0, 0, 0);
        acc2 = __builtin_amdgcn_mfma_f32_16x16x32_bf16(af, b2, acc2, 0, 0, 0);
        acc3 = __builtin_amdgcn_mfma_f32_16x16x32_bf16(af, b3, acc3, 0, 0, 0);
    }
#pragma unroll
    for (int reg = 0; reg < 4; ++reg) {
        int r = rowBase + quad * 4 + reg;
        if (r < N) {
            float dsc = dis[r];
            unsigned short* hp = Hbs + (size_t)r * 64 + m16;
            hp[0]  = f2bf(acc0[reg] * dsc);
            hp[16] = f2bf(acc1[reg] * dsc);
            hp[32] = f2bf(acc2[reg] * dsc);
            hp[48] = f2bf(acc3[reg] * dsc);
        }
    }
}

// ------- gather-aggregate: wave per 4 nodes, 2 edges per wave-instruction -------
// MODE 1: out = relu row, stored bf16 (feeds bf16 mmx)
// MODE 2: relu row, dot with W3, write colS[i] = dot*dis and out[i] = dot*dis^2 + b3
#define GNODE2(ACC, RA, RB)                                                    \
    {                                                                          \
        int j0 = max(RA - base, 0);                                            \
        int j1 = min(RB - base, cnt);                                          \
        int j = j0;                                                            \
        for (; j + 4 <= j1; j += 4) {                                          \
            unsigned o1 = __shfl(eoff, j + g, 64);                             \
            unsigned o2 = __shfl(eoff, j + 2 + g, 64);                         \
            unsigned d1 = *(const unsigned*)(hbase + o1);                      \
            unsigned d2 = *(const unsigned*)(hbase + o2);                      \
            ACC.x += __uint_as_float(d1 << 16);                                \
            ACC.y += __uint_as_float(d1 & 0xFFFF0000u);                        \
            ACC.x += __uint_as_float(d2 << 16);                                \
            ACC.y += __uint_as_float(d2 & 0xFFFF0000u);                        \
        }                                                                      \
        for (; j < j1; j += 2) {                                               \
            int idx = j + g;                                                   \
            bool valid = idx < j1;                                             \
            unsigned o = __shfl(eoff, valid ? idx : j0, 64);                   \
            unsigned d = *(const unsigned*)(hbase + o);                        \
            d = valid ? d : 0u;                                                \
            ACC.x += __uint_as_float(d << 16);                                 \
            ACC.y += __uint_as_float(d & 0xFFFF0000u);                         \
        }                                                                      \
    }

template <int MODE>
__global__ __launch_bounds__(256) void k_gather64(const unsigned short* __restrict__ Hbs,
                                                  const int* __restrict__ esrc,
                                                  const int* __restrict__ rowStart,
                                                  const float* __restrict__ dis,
                                                  const float* __restrict__ b,
                                                  unsigned short* __restrict__ outB,
                                                  const float* __restrict__ W3,
                                                  const float* __restrict__ b3,
                                                  float* __restrict__ colS,
                                                  float* __restrict__ outF,
                                                  int N) {
    int lane = threadIdx.x & 63;
    int l = lane & 31;
    int g = lane >> 5;
    int wave = (blockIdx.x * 256 + threadIdx.x) >> 6;
    int g0 = wave * 4;
    if (g0 >= N) return;
    const char* hbase = (const char*)Hbs + l * 4;   // dword column of each row

    int rb = rowStart[min(g0 + lane, N)];
    int R0 = __shfl(rb, 0, 64), R1 = __shfl(rb, 1, 64);
    int R2 = __shfl(rb, 2, 64), R3 = __shfl(rb, 3, 64);
    int R4 = __shfl(rb, 4, 64);
    float dv = dis[min(g0 + lane, N - 1)];
    float d0 = __shfl(dv, 0, 64), d1 = __shfl(dv, 1, 64);
    float d2 = __shfl(dv, 2, 64), d3 = __shfl(dv, 3, 64);
    float2 bl = ((const float2*)b)[l];

    float2 a0 = {0.f, 0.f}, a1 = {0.f, 0.f}, a2 = {0.f, 0.f}, a3 = {0.f, 0.f};
    {
        int n0 = (g == 0) ? g0 : min(g0 + 2, N - 1);
        int n1 = (g == 0) ? min(g0 + 1, N - 1) : min(g0 + 3, N - 1);
        unsigned s0 = *(const unsigned*)(hbase + (size_t)n0 * 128);
        unsigned s1 = *(const unsigned*)(hbase + (size_t)n1 * 128);
        float2 f0 = {__uint_as_float(s0 << 16), __uint_as_float(s0 & 0xFFFF0000u)};
        float2 f1 = {__uint_as_float(s1 << 16), __uint_as_float(s1 & 0xFFFF0000u)};
        if (g == 0) { a0 = f0; a1 = f1; } else { a2 = f0; a3 = f1; }
    }

    for (int base = R0; base < R4; base += 64) {
        int cnt = min(64, R4 - base);
        unsigned eoff = (lane < cnt) ? (unsigned)esrc[base + lane] : 0u;
        GNODE2(a0, R0, R1)
        GNODE2(a1, R1, R2)
        GNODE2(a2, R2, R3)
        GNODE2(a3, R3, R4)
    }

    a0.x += __shfl_xor(a0.x, 32, 64); a0.y += __shfl_xor(a0.y, 32, 64);
    a1.x += __shfl_xor(a1.x, 32, 64); a1.y += __shfl_xor(a1.y, 32, 64);
    a2.x += __shfl_xor(a2.x, 32, 64); a2.y += __shfl_xor(a2.y, 32, 64);
    a3.x += __shfl_xor(a3.x, 32, 64); a3.y += __shfl_xor(a3.y, 32, 64);

    float2 v0 = {fmaxf(a0.x * d0 + bl.x, 0.f), fmaxf(a0.y * d0 + bl.y, 0.f)};
    float2 v1 = {fmaxf(a1.x * d1 + bl.x, 0.f), fmaxf(a1.y * d1 + bl.y, 0.f)};
    float2 v2 = {fmaxf(a2.x * d2 + bl.x, 0.f), fmaxf(a2.y * d2 + bl.y, 0.f)};
    float2 v3 = {fmaxf(a3.x * d3 + bl.x, 0.f), fmaxf(a3.y * d3 + bl.y, 0.f)};

    if (MODE == 1) {
        unsigned p0 = (unsigned)f2bf(v0.x) | ((unsigned)f2bf(v0.y) << 16);
        unsigned p1 = (unsigned)f2bf(v1.x) | ((unsigned)f2bf(v1.y) << 16);
        unsigned p2 = (unsigned)f2bf(v2.x) | ((unsigned)f2bf(v2.y) << 16);
        unsigned p3 = (unsigned)f2bf(v3.x) | ((unsigned)f2bf(v3.y) << 16);
        unsigned* ob = (unsigned*)outB;
        if (g == 0) {
            ob[(size_t)g0 * 32 + l] = p0;
            if (g0 + 1 < N) ob[(size_t)(g0 + 1) * 32 + l] = p1;
        } else {
            if (g0 + 2 < N) ob[(size_t)(g0 + 2) * 32 + l] = p2;
            if (g0 + 3 < N) ob[(size_t)(g0 + 3) * 32 + l] = p3;
        }
    } else {
        float2 w3 = ((const float2*)W3)[l];
        float t0 = v0.x * w3.x + v0.y * w3.y;
        float t1 = v1.x * w3.x + v1.y * w3.y;
        float t2 = v2.x * w3.x + v2.y * w3.y;
        float t3 = v3.x * w3.x + v3.y * w3.y;
#pragma unroll
        for (int off = 1; off <= 16; off <<= 1) {
            t0 += __shfl_xor(t0, off, 64);
            t1 += __shfl_xor(t1, off, 64);
            t2 += __shfl_xor(t2, off, 64);
            t3 += __shfl_xor(t3, off, 64);
        }
        if (lane == 0) {
            float bb = b3[0];
            colS[g0] = t0 * d0;
            outF[g0] = t0 * d0 * d0 + bb;
            if (g0 + 1 < N) { colS[g0 + 1] = t1 * d1; outF[g0 + 1] = t1 * d1 * d1 + bb; }
            if (g0 + 2 < N) { colS[g0 + 2] = t2 * d2; outF[g0 + 2] = t2 * d2 * d2 + bb; }
            if (g0 + 3 < N) { colS[g0 + 3] = t3 * d3; outF[g0 + 3] = t3 * d3 * d3 + bb; }
        }
    }
}

// out[i] += dis[i] * sum colS[esrc>>7]
__global__ __launch_bounds__(256) void k_gather1(const float* __restrict__ colS,
                                                 const int* __restrict__ esrc,
                                                 const int* __restrict__ rowStart,
                                                 const float* __restrict__ dis,
                                                 float* __restrict__ out, int N) {
    int i = blockIdx.x * 256 + threadIdx.x;
    if (i >= N) return;
    int r0 = rowStart[i], r1 = rowStart[i + 1];
    float acc = 0.0f;
    for (int e = r0; e < r1; ++e) acc += colS[((unsigned)esrc[e]) >> 7];
    out[i] += acc * dis[i];
}

extern "C" void kernel_launch(void* const* d_in, const int* in_sizes, int n_in,
                              void* d_out, int out_size, void* d_ws, size_t ws_size,
                              hipStream_t stream) {
    const float* x  = (const float*)d_in[0];
    const int*   ei = (const int*)d_in[1];
    const float* W1 = (const float*)d_in[2];
    const float* b1 = (const float*)d_in[3];
    const float* W2 = (const float*)d_in[4];
    const float* b2 = (const float*)d_in[5];
    const float* W3 = (const float*)d_in[6];
    const float* b3 = (const float*)d_in[7];
    float* out = (float*)d_out;

    const int N = in_sizes[0] / IN_DIM;     // 100000
    const int E = in_sizes[1] / 2;          // 1600000
    const int* src = ei;
    const int* dst = ei + E;
    const int NC = (N + 255) >> 8;          // 391 coarse buckets
    const int NBLK = (E + EPB - 1) / EPB;   // 196 partition blocks

    // ---- workspace layout ----
    char* w = (char*)d_ws;
    auto alloc = [&](size_t bytes) {
        char* p = w;
        w += (bytes + 1023) & ~(size_t)1023;
        return p;
    };
    float*          dis        = (float*)alloc((size_t)N * 4);
    unsigned short* Hbs        = (unsigned short*)alloc((size_t)N * 64 * 2);
    unsigned short* Hb1        = (unsigned short*)alloc((size_t)N * 64 * 2);
    float*          colS       = (float*)alloc((size_t)N * 4);
    int*            rowStart   = (int*)alloc((size_t)(N + 1) * 4);
    int*            bktTotal   = (int*)alloc((size_t)MAXC * 4);
    int*            coarseStart= (int*)alloc((size_t)(MAXC + 1) * 4);
    int*            hmat       = (int*)alloc((size_t)MAXB * MAXC * 4);
    int*            esrc       = (int*)alloc((size_t)E * 4);
    int*            tmp1       = (int*)alloc((size_t)E * 4);

    const int NB_N  = (N + 255) / 256;
    const int NB_MX = (N + 63) / 64;                    // MFMA transform blocks
    const int NB_G4 = ((N + 3) / 4 * 64 + 255) / 256;   // 4 nodes per wave

    // ---- deterministic partition (no global atomics, no memset) ----
    k_hist2<<<NBLK, 256, 0, stream>>>(dst, hmat, E, NC);
    k_bktscan<<<NC, 256, 0, stream>>>(hmat, bktTotal, NBLK, NC);
    k_cscan<<<1, 512, 0, stream>>>(bktTotal, coarseStart, rowStart, NC, N, E);
    k_part1<<<NBLK, 256, 0, stream>>>(src, dst, hmat, coarseStart, tmp1, E, NC);
    k_degplace<<<NC, DPT, 0, stream>>>(tmp1, coarseStart, dis, rowStart, esrc, N);

    // ---- layer 1: mmx fp32->bf16, gather -> bf16 rows ----
    k_mmx<IN_DIM, float><<<NB_MX, 256, 0, stream>>>(x, W1, dis, Hbs, N);
    k_gather64<1><<<NB_G4, 256, 0, stream>>>(Hbs, esrc, rowStart, dis, b1,
                                             Hb1, nullptr, nullptr, nullptr, nullptr, N);

    // ---- layer 2: mmx bf16 input, gather fused with W3 dot ----
    k_mmx<HID, unsigned short><<<NB_MX, 256, 0, stream>>>(Hb1, W2, dis, Hbs, N);
    k_gather64<2><<<NB_G4, 256, 0, stream>>>(Hbs, esrc, rowStart, dis, b2,
                                             nullptr, W3, b3, colS, out, N);

    // ---- layer 3 aggregation ----
    k_gather1<<<NB_N, 256, 0, stream>>>(colS, esrc, rowStart, dis, out, N);
}